// Round 2
// baseline (16104.834 us; speedup 1.0000x reference)
//
#include <hip/hip_runtime.h>
#include <hip/hip_bf16.h>
#include <cstdint>
#include <cstddef>

using bf16 = __hip_bfloat16;

static constexpr int BBATCH = 8, CCH = 64, NNODE = 170, TT = 256;
static constexpr size_t HSZ  = (size_t)BBATCH * CCH * NNODE * TT;  // 22282240
static constexpr size_t H7SZ = (size_t)CCH * NNODE * TT;           // 2785280
static constexpr int GN = NNODE * NNODE;                           // 28900

__device__ __forceinline__ float b2f(bf16 v) { return __bfloat162float(v); }
__device__ __forceinline__ bf16  f2b(float v) { return __float2bfloat16(v); }

// ---------------- threefry2x32 (JAX-compatible, partitionable) ----------------
__device__ __forceinline__ unsigned rotl32(unsigned v, int d) { return (v << d) | (v >> (32 - d)); }

__device__ void threefry2x32(unsigned k0, unsigned k1, unsigned x0, unsigned x1,
                             unsigned& y0, unsigned& y1) {
  unsigned ks0 = k0, ks1 = k1, ks2 = k0 ^ k1 ^ 0x1BD11BDAu;
  x0 += ks0; x1 += ks1;
  const int ra[4] = {13, 15, 26, 6};
  const int rb[4] = {17, 29, 16, 24};
#pragma unroll
  for (int r = 0; r < 4; r++) { x0 += x1; x1 = rotl32(x1, ra[r]); x1 ^= x0; }
  x0 += ks1; x1 += ks2 + 1u;
#pragma unroll
  for (int r = 0; r < 4; r++) { x0 += x1; x1 = rotl32(x1, rb[r]); x1 ^= x0; }
  x0 += ks2; x1 += ks0 + 2u;
#pragma unroll
  for (int r = 0; r < 4; r++) { x0 += x1; x1 = rotl32(x1, ra[r]); x1 ^= x0; }
  x0 += ks0; x1 += ks1 + 3u;
#pragma unroll
  for (int r = 0; r < 4; r++) { x0 += x1; x1 = rotl32(x1, rb[r]); x1 ^= x0; }
  x0 += ks1; x1 += ks2 + 4u;
#pragma unroll
  for (int r = 0; r < 4; r++) { x0 += x1; x1 = rotl32(x1, ra[r]); x1 ^= x0; }
  x0 += ks2; x1 += ks0 + 5u;
  y0 = x0; y1 = x1;
}

// foldlike split: key_j = threefry(key, hi=0, lo=j); base key seed 42 -> (0,42)
__global__ void k_keys(unsigned* keys) {
  int j = threadIdx.x;
  if (j < 4) {
    unsigned y0, y1;
    threefry2x32(0u, 42u, 0u, (unsigned)j, y0, y1);
    keys[2*j] = y0; keys[2*j+1] = y1;
  }
}

// partitionable random_bits: bits[i] = y0 ^ y1 of threefry(key, 0, i)
__global__ __launch_bounds__(256) void k_gumbel(const unsigned* __restrict__ keys,
                                                float* __restrict__ g) {
  int idx = blockIdx.x * 256 + threadIdx.x;
  if (idx >= 4 * GN) return;
  int w = idx / GN, i = idx % GN;
  unsigned y0, y1;
  threefry2x32(keys[2*w], keys[2*w+1], 0u, (unsigned)i, y0, y1);
  unsigned bits = y0 ^ y1;
  unsigned fb = (bits >> 9) | 0x3f800000u;
  float u = __uint_as_float(fb) - 1.0f;
  g[idx] = -logf(-logf(u + 1e-20f) + 1e-20f);
}

// ---------------- adj = softmax(relu(nv1@nv2), axis=1) ----------------
__global__ __launch_bounds__(256) void k_adj(const float* __restrict__ nv1,
                                             const float* __restrict__ nv2,
                                             float* __restrict__ adj) {
  int i = blockIdx.x, j = threadIdx.x;
  __shared__ float red[256];
  float val = 0.f, r = -1e30f;
  if (j < NNODE) {
    float acc = 0.f;
    for (int k = 0; k < 10; k++) acc += nv1[i*10+k] * nv2[k*NNODE+j];
    val = acc > 0.f ? acc : 0.f;
    r = val;
  }
  red[j] = r; __syncthreads();
  for (int s = 128; s; s >>= 1) { if (j < s) red[j] = fmaxf(red[j], red[j+s]); __syncthreads(); }
  float m = red[0]; __syncthreads();
  float e = (j < NNODE) ? expf(val - m) : 0.f;
  red[j] = e; __syncthreads();
  for (int s = 128; s; s >>= 1) { if (j < s) red[j] += red[j+s]; __syncthreads(); }
  if (j < NNODE) adj[i*NNODE+j] = e / red[0];
}

// ---------------- fused branch: conv5(edgepad)+leaky + conv3 + tanh ----------------
// grid (NNODE, 8, BBATCH), block 256 = (tl 0..31) x (og 0..7); T-tile 32.
// b<7: writes bf16 hout. b==7: writes fp32 h7f + Spart (8 q-slices). 19.5 KB LDS.
__global__ __launch_bounds__(256) void k_branch(
    const float* __restrict__ src, int par,
    const float* __restrict__ w5f, const float* __restrict__ b5p,
    const float* __restrict__ w3f, const float* __restrict__ b3p,
    bf16* __restrict__ hout, float* __restrict__ h7f, float* __restrict__ Spart) {
  const int n = blockIdx.x, q = blockIdx.y, b = blockIdx.z;
  const int tid = threadIdx.x;
  const int tl = tid & 31, og = tid >> 5;
  __shared__ float xs[64][40];    // cols 0..37 used
  __shared__ float h1s[64][36];   // cols 0..33 used
  const int t0 = q * 32;
  const bool b7 = (b == 7);

  for (int i = tid; i < 64 * 38; i += 256) {
    int c = i / 38, pl = i % 38;
    int t = t0 + pl - 3; t = t < 0 ? 0 : (t > 255 ? 255 : t);
    size_t base = ((size_t)b * 64 + c) * NNODE + n;
    float v = (par >= 0) ? src[base * 512 + 2 * t + par] : src[base * TT + t];
    xs[c][pl] = v;
  }
  __syncthreads();

  // conv5 + leaky: positions tl (0..31)
  for (int oo = 0; oo < 8; oo++) {
    const int o = og * 8 + oo;
    float acc = b5p[o];
    for (int c = 0; c < 64; c++) {
      const float* wp = &w5f[(o * 64 + c) * 5];
      const float* xp = &xs[c][tl];
#pragma unroll
      for (int k = 0; k < 5; k++) acc += wp[k] * xp[k];
    }
    h1s[o][tl] = acc >= 0.f ? acc : 0.01f * acc;
  }
  // extra positions 32,33
  if (tl < 16) {
    const int o = og * 8 + (tl & 7);
    const int pos = 32 + (tl >> 3);
    float acc = b5p[o];
    for (int c = 0; c < 64; c++) {
      const float* wp = &w5f[(o * 64 + c) * 5];
      const float* xp = &xs[c][pos];
#pragma unroll
      for (int k = 0; k < 5; k++) acc += wp[k] * xp[k];
    }
    h1s[o][pos] = acc >= 0.f ? acc : 0.01f * acc;
  }
  __syncthreads();

  // conv3 + tanh
  for (int oo = 0; oo < 8; oo++) {
    const int o = og * 8 + oo;
    float acc = b3p[o];
    for (int c = 0; c < 64; c++) {
      const float* wp = &w3f[(o * 64 + c) * 3];
      const float* hp = &h1s[c][tl];
#pragma unroll
      for (int k = 0; k < 3; k++) acc += wp[k] * hp[k];
    }
    float v = tanhf(acc);
    if (b7) {
      h7f[((size_t)o * NNODE + n) * TT + t0 + tl] = v;
      float s = v;
#pragma unroll
      for (int m = 16; m; m >>= 1) s += __shfl_xor(s, m, 32);
      if (tl == 0) Spart[(q * 64 + o) * NNODE + n] = s;
    } else {
      hout[(((size_t)b * 64 + o) * NNODE + n) * TT + t0 + tl] = f2b(v);
    }
  }
}

__global__ __launch_bounds__(256) void k_sred(const float* __restrict__ Spart, float* __restrict__ S) {
  int idx = blockIdx.x * 256 + threadIdx.x;
  if (idx >= CCH * NNODE) return;
  float acc = 0.f;
#pragma unroll
  for (int qq = 0; qq < 8; qq++) acc += Spart[qq * 10880 + idx];
  S[idx] = acc;
}

// ---------------- graph-gen small kernels (all fp32) ----------------
__global__ __launch_bounds__(256) void k_s1(const float* __restrict__ S, const float* __restrict__ adj,
                                            float* __restrict__ S1) {
  int idx = blockIdx.x * 256 + threadIdx.x;
  if (idx >= CCH * NNODE) return;
  int c = idx / NNODE, m = idx % NNODE;
  float acc = 0.f;
  for (int n = 0; n < NNODE; n++) acc += S[c*NNODE+n] * adj[n*NNODE+m];
  S1[idx] = acc;
}

__global__ __launch_bounds__(256) void k_h0(const float* __restrict__ S, const float* __restrict__ S1,
                                            const float* __restrict__ ggw, const float* __restrict__ ggb,
                                            float* __restrict__ H0) {
  int idx = blockIdx.x * 256 + threadIdx.x;
  if (idx >= NNODE * CCH) return;
  int n = idx >> 6, o = idx & 63;
  float acc = 256.f * ggb[o];
  for (int c = 0; c < 64; c++)
    acc += ggw[o*128 + c] * S[c*NNODE+n] + ggw[o*128 + 64 + c] * S1[c*NNODE+n];
  H0[n*64 + o] = acc;
}

__global__ __launch_bounds__(256) void k_a1(const float* __restrict__ H0, const float* __restrict__ fc0w,
                                            const float* __restrict__ fc0b, float* __restrict__ A1) {
  int idx = blockIdx.x * 256 + threadIdx.x;
  if (idx >= GN) return;
  int i = idx / NNODE, j = idx % NNODE;
  float acc = fc0b[j];
  for (int o = 0; o < 64; o++) acc += H0[i*64+o] * fc0w[j*64+o];
  A1[idx] = tanhf(acc);
}

__global__ __launch_bounds__(256) void k_a2(const float* __restrict__ A1, const float* __restrict__ fc1w,
                                            const float* __restrict__ fc1b, float* __restrict__ A2) {
  int idx = blockIdx.x * 256 + threadIdx.x;
  if (idx >= NNODE * 340) return;
  int i = idx / 340, j = idx % 340;
  float acc = fc1b[j];
  for (int k = 0; k < NNODE; k++) acc += A1[i*NNODE+k] * fc1w[j*NNODE+k];
  A2[idx] = tanhf(acc);
}

__global__ __launch_bounds__(256) void k_a3(const float* __restrict__ A2, const float* __restrict__ fc2w,
                                            const float* __restrict__ fc2b, float* __restrict__ A3) {
  int idx = blockIdx.x * 256 + threadIdx.x;
  if (idx >= GN) return;
  int i = idx / NNODE, j = idx % NNODE;
  float acc = fc2b[j];
  for (int k = 0; k < 340; k++) acc += A2[i*340+k] * fc2w[j*340+k];
  A3[idx] = tanhf(acc);
}

// row argmax of (A3+g) -> dadj = onehot*a + adj*(1-a); optional fp32 out tail
__global__ __launch_bounds__(256) void k_dadj(const float* __restrict__ A3, const float* __restrict__ g,
                                              const float* __restrict__ adj, const float* __restrict__ a_in,
                                              float* __restrict__ dadj, float* __restrict__ out_tail) {
  int i = blockIdx.x, j = threadIdx.x;
  __shared__ float vred[256];
  __shared__ int   ired[256];
  float v = -1e30f;
  if (j < NNODE) v = A3[i*NNODE+j] + g[i*NNODE+j];
  vred[j] = v; ired[j] = j;
  __syncthreads();
  for (int s = 128; s; s >>= 1) {
    if (j < s) {
      if (vred[j+s] > vred[j]) { vred[j] = vred[j+s]; ired[j] = ired[j+s]; }
    }
    __syncthreads();
  }
  int jmax = ired[0];
  float a = a_in[0];
  if (j < NNODE) {
    float la = (j == jmax && jmax != i) ? 1.f : 0.f;
    float dv = la * a + adj[i*NNODE+j] * (1.f - a);
    dadj[i*NNODE+j] = dv;
    if (out_tail) out_tail[i*NNODE+j] = dv;
  }
}

// ---------------- hA = einsum('bcnt,nm->bcmt', h, dadj) ----------------
__global__ __launch_bounds__(256) void k_hA(const bf16* __restrict__ h, const float* __restrict__ h7f,
                                            const float* __restrict__ dadj,
                                            bf16* __restrict__ hA, float* __restrict__ hA7f) {
  size_t idx = (size_t)blockIdx.x * 256 + threadIdx.x;
  int t = (int)(idx & 255);
  size_t r = idx >> 8;                 // (b*64+c)*170 + m
  int m = (int)(r % NNODE);
  int bc = (int)(r / NNODE);
  int b = bc >> 6, c = bc & 63;
  float acc = 0.f;
  if (b == 7) {
    const float* hp = h7f + ((size_t)c * NNODE) * TT + t;
#pragma unroll 4
    for (int nn = 0; nn < NNODE; nn++) acc += hp[(size_t)nn * TT] * dadj[nn*NNODE+m];
    hA7f[((size_t)c * NNODE + m) * TT + t] = acc;
  } else {
    const bf16* hp = h + ((size_t)bc * NNODE) * TT + t;
#pragma unroll 4
    for (int nn = 0; nn < NNODE; nn++) acc += b2f(hp[(size_t)nn * TT]) * dadj[nn*NNODE+m];
    hA[idx] = f2b(acc);
  }
}

// ---------------- channel mix + residual + per-step epilogue ----------------
// epi: 1: outo = x_odd*tanh(acc); 2: oute = x_even*tanh(acc); 3: outo -= acc; 4: oute += acc
__global__ __launch_bounds__(256) void k_mix(const bf16* __restrict__ h, const bf16* __restrict__ hA,
                                             const float* __restrict__ h7f, const float* __restrict__ hA7f,
                                             const float* __restrict__ dcwf, const float* __restrict__ dcb,
                                             const float* __restrict__ x,
                                             float* __restrict__ oute, float* __restrict__ outo, int epi) {
  size_t idx = (size_t)blockIdx.x * 256 + threadIdx.x;
  int t = (int)(idx & 255);
  size_t r = idx >> 8;                 // (b*64+o)*170+n
  int n = (int)(r % NNODE);
  int bo = (int)(r / NNODE);
  int b = bo >> 6, o = bo & 63;
  float acc = dcb[o];
  if (b == 7) {
    acc += h7f[((size_t)o * NNODE + n) * TT + t];
    for (int cc = 0; cc < 64; cc++) {
      size_t off = ((size_t)cc * NNODE + n) * TT + t;
      acc += dcwf[o*128+cc] * h7f[off] + dcwf[o*128+64+cc] * hA7f[off];
    }
  } else {
    size_t bbase = ((size_t)(b*64) * NNODE + n) * TT + t;
    acc += b2f(h[idx]);
    for (int cc = 0; cc < 64; cc++) {
      size_t off = bbase + (size_t)cc * (NNODE * TT);
      acc += dcwf[o*128+cc] * b2f(h[off]) + dcwf[o*128+64+cc] * b2f(hA[off]);
    }
  }
  if (epi == 1) {
    outo[idx] = x[r*512 + 2*t + 1] * tanhf(acc);
  } else if (epi == 2) {
    oute[idx] = x[r*512 + 2*t] * tanhf(acc);
  } else if (epi == 3) {
    outo[idx] -= acc;
  } else {
    oute[idx] += acc;
  }
}

// ---------------- host ----------------
extern "C" void kernel_launch(void* const* d_in, const int* in_sizes, int n_in,
                              void* d_out, int out_size, void* d_ws, size_t ws_size,
                              hipStream_t stream) {
  const float* x    = (const float*)d_in[0];
  const float* nv1  = (const float*)d_in[1];
  const float* nv2  = (const float*)d_in[2];
  const float* a_in = (const float*)d_in[3];
  const float *w5[4], *b5[4], *w3[4], *b3[4];
  for (int s = 0; s < 4; s++) {
    w5[s] = (const float*)d_in[4 + 4*s];
    b5[s] = (const float*)d_in[5 + 4*s];
    w3[s] = (const float*)d_in[6 + 4*s];
    b3[s] = (const float*)d_in[7 + 4*s];
  }
  const float* ggw  = (const float*)d_in[20];
  const float* ggb  = (const float*)d_in[21];
  const float* fc0w = (const float*)d_in[22];
  const float* fc0b = (const float*)d_in[23];
  const float* fc1w = (const float*)d_in[24];
  const float* fc1b = (const float*)d_in[25];
  const float* fc2w = (const float*)d_in[26];
  const float* fc2b = (const float*)d_in[27];
  const float* dcw  = (const float*)d_in[28];
  const float* dcb  = (const float*)d_in[29];

  char* p = (char*)d_ws;
  size_t used = 0;
  auto alloc = [&](size_t bytes) -> char* {
    char* r = p + used;
    used += (bytes + 255) & ~(size_t)255;
    return r;
  };
  float* adjW   = (float*)alloc(GN*4);
  float* dadjW  = (float*)alloc(GN*4);
  float* gW     = (float*)alloc(4*GN*4);
  unsigned* keys= (unsigned*)alloc(8*4);
  float* Sa     = (float*)alloc(CCH*NNODE*4);
  float* Sb     = (float*)alloc(CCH*NNODE*4);
  float* Spart  = (float*)alloc(8*CCH*NNODE*4);
  float* S1     = (float*)alloc(CCH*NNODE*4);
  float* H0     = (float*)alloc(NNODE*CCH*4);
  float* A1     = (float*)alloc(GN*4);
  float* A2     = (float*)alloc(NNODE*340*4);
  float* A3     = (float*)alloc(GN*4);
  bf16* H1      = (bf16*)alloc(HSZ*2);
  bf16* H2      = (bf16*)alloc(HSZ*2);
  bf16* HA      = (bf16*)alloc(HSZ*2);
  float* h7fA   = (float*)alloc(H7SZ*4);
  float* h7fB   = (float*)alloc(H7SZ*4);
  float* hA7f   = (float*)alloc(H7SZ*4);
  if (used > ws_size) return;  // signature: output stays zero -> error exactly 5.0625

  float* oute = (float*)d_out;
  float* outo = oute + HSZ;
  float* tail = oute + 2*HSZ;

  const int HBLK = (int)(HSZ / 256);   // 87040
  dim3 bgrid(NNODE, 8, BBATCH);

  k_adj<<<NNODE, 256, 0, stream>>>(nv1, nv2, adjW);
  k_keys<<<1, 64, 0, stream>>>(keys);
  k_gumbel<<<(4*GN + 255)/256, 256, 0, stream>>>(keys, gW);

  auto graph_pipe = [&](const float* S, const float* gstep, float* tailp) {
    k_s1<<<43, 256, 0, stream>>>(S, adjW, S1);
    k_h0<<<43, 256, 0, stream>>>(S, S1, ggw, ggb, H0);
    k_a1<<<113, 256, 0, stream>>>(H0, fc0w, fc0b, A1);
    k_a2<<<226, 256, 0, stream>>>(A1, fc1w, fc1b, A2);
    k_a3<<<113, 256, 0, stream>>>(A2, fc2w, fc2b, A3);
    k_dadj<<<NNODE, 256, 0, stream>>>(A3, gstep, adjW, a_in, dadjW, tailp);
  };

  // step 1: branch(xe) -> x1 ; d = xo*tanh(x1) -> outo
  k_branch<<<bgrid, 256, 0, stream>>>(x, 0, w5[0], b5[0], w3[0], b3[0], H1, h7fA, Spart);
  k_sred<<<43, 256, 0, stream>>>(Spart, Sa);
  graph_pipe(Sa, gW, nullptr);
  k_hA<<<HBLK, 256, 0, stream>>>(H1, h7fA, dadjW, HA, hA7f);
  k_mix<<<HBLK, 256, 0, stream>>>(H1, HA, h7fA, hA7f, dcw, dcb, x, oute, outo, 1);

  // step 2: branch(xo) -> x2 ; c = xe*tanh(x2) -> oute
  k_branch<<<bgrid, 256, 0, stream>>>(x, 1, w5[1], b5[1], w3[1], b3[1], H1, h7fA, Spart);
  k_sred<<<43, 256, 0, stream>>>(Spart, Sa);
  graph_pipe(Sa, gW + GN, nullptr);
  k_hA<<<HBLK, 256, 0, stream>>>(H1, h7fA, dadjW, HA, hA7f);
  k_mix<<<HBLK, 256, 0, stream>>>(H1, HA, h7fA, hA7f, dcw, dcb, x, oute, outo, 2);

  // steps 3 & 4: run both branches BEFORE either epilogue overwrites d_out
  k_branch<<<bgrid, 256, 0, stream>>>(oute, -1, w5[2], b5[2], w3[2], b3[2], H1, h7fA, Spart);
  k_sred<<<43, 256, 0, stream>>>(Spart, Sa);
  k_branch<<<bgrid, 256, 0, stream>>>(outo, -1, w5[3], b5[3], w3[3], b3[3], H2, h7fB, Spart);
  k_sred<<<43, 256, 0, stream>>>(Spart, Sb);

  // step 3 rest: outo = d - x3
  graph_pipe(Sa, gW + 2*GN, nullptr);
  k_hA<<<HBLK, 256, 0, stream>>>(H1, h7fA, dadjW, HA, hA7f);
  k_mix<<<HBLK, 256, 0, stream>>>(H1, HA, h7fA, hA7f, dcw, dcb, x, oute, outo, 3);

  // step 4 rest: oute = c + x4 ; dadj -> tail
  graph_pipe(Sb, gW + 3*GN, tail);
  k_hA<<<HBLK, 256, 0, stream>>>(H2, h7fB, dadjW, HA, hA7f);
  k_mix<<<HBLK, 256, 0, stream>>>(H2, HA, h7fB, hA7f, dcw, dcb, x, oute, outo, 4);

  (void)in_sizes; (void)n_in; (void)out_size;
}

// Round 3
// 4338.754 us; speedup vs baseline: 3.7119x; 3.7119x over previous
//
#include <hip/hip_runtime.h>
#include <hip/hip_bf16.h>
#include <cstdint>
#include <cstddef>

using bf16 = __hip_bfloat16;

static constexpr int BBATCH = 8, CCH = 64, NNODE = 170, TT = 256;
static constexpr size_t HSZ  = (size_t)BBATCH * CCH * NNODE * TT;  // 22282240
static constexpr size_t H7SZ = (size_t)CCH * NNODE * TT;           // 2785280
static constexpr int GN = NNODE * NNODE;                           // 28900

__device__ __forceinline__ float b2f(bf16 v) { return __bfloat162float(v); }
__device__ __forceinline__ bf16  f2b(float v) { return __float2bfloat16(v); }

union BfU { bf16 h; unsigned short s; };
__device__ __forceinline__ unsigned pack2(float a, float b) {
  BfU x, y; x.h = f2b(a); y.h = f2b(b);
  return ((unsigned)y.s << 16) | x.s;
}

// ---------------- threefry2x32 (JAX-compatible, partitionable) ----------------
__device__ __forceinline__ unsigned rotl32(unsigned v, int d) { return (v << d) | (v >> (32 - d)); }

__device__ void threefry2x32(unsigned k0, unsigned k1, unsigned x0, unsigned x1,
                             unsigned& y0, unsigned& y1) {
  unsigned ks0 = k0, ks1 = k1, ks2 = k0 ^ k1 ^ 0x1BD11BDAu;
  x0 += ks0; x1 += ks1;
  const int ra[4] = {13, 15, 26, 6};
  const int rb[4] = {17, 29, 16, 24};
#pragma unroll
  for (int r = 0; r < 4; r++) { x0 += x1; x1 = rotl32(x1, ra[r]); x1 ^= x0; }
  x0 += ks1; x1 += ks2 + 1u;
#pragma unroll
  for (int r = 0; r < 4; r++) { x0 += x1; x1 = rotl32(x1, rb[r]); x1 ^= x0; }
  x0 += ks2; x1 += ks0 + 2u;
#pragma unroll
  for (int r = 0; r < 4; r++) { x0 += x1; x1 = rotl32(x1, ra[r]); x1 ^= x0; }
  x0 += ks0; x1 += ks1 + 3u;
#pragma unroll
  for (int r = 0; r < 4; r++) { x0 += x1; x1 = rotl32(x1, rb[r]); x1 ^= x0; }
  x0 += ks1; x1 += ks2 + 4u;
#pragma unroll
  for (int r = 0; r < 4; r++) { x0 += x1; x1 = rotl32(x1, ra[r]); x1 ^= x0; }
  x0 += ks2; x1 += ks0 + 5u;
  y0 = x0; y1 = x1;
}

__global__ void k_keys(unsigned* keys) {
  int j = threadIdx.x;
  if (j < 4) {
    unsigned y0, y1;
    threefry2x32(0u, 42u, 0u, (unsigned)j, y0, y1);
    keys[2*j] = y0; keys[2*j+1] = y1;
  }
}

__global__ __launch_bounds__(256) void k_gumbel(const unsigned* __restrict__ keys,
                                                float* __restrict__ g) {
  int idx = blockIdx.x * 256 + threadIdx.x;
  if (idx >= 4 * GN) return;
  int w = idx / GN, i = idx % GN;
  unsigned y0, y1;
  threefry2x32(keys[2*w], keys[2*w+1], 0u, (unsigned)i, y0, y1);
  unsigned bits = y0 ^ y1;
  unsigned fb = (bits >> 9) | 0x3f800000u;
  float u = __uint_as_float(fb) - 1.0f;
  g[idx] = -logf(-logf(u + 1e-20f) + 1e-20f);
}

// ---------------- adj = softmax(relu(nv1@nv2), axis=1) ----------------
__global__ __launch_bounds__(256) void k_adj(const float* __restrict__ nv1,
                                             const float* __restrict__ nv2,
                                             float* __restrict__ adj) {
  int i = blockIdx.x, j = threadIdx.x;
  __shared__ float red[256];
  float val = 0.f, r = -1e30f;
  if (j < NNODE) {
    float acc = 0.f;
    for (int k = 0; k < 10; k++) acc += nv1[i*10+k] * nv2[k*NNODE+j];
    val = acc > 0.f ? acc : 0.f;
    r = val;
  }
  red[j] = r; __syncthreads();
  for (int s = 128; s; s >>= 1) { if (j < s) red[j] = fmaxf(red[j], red[j+s]); __syncthreads(); }
  float m = red[0]; __syncthreads();
  float e = (j < NNODE) ? expf(val - m) : 0.f;
  red[j] = e; __syncthreads();
  for (int s = 128; s; s >>= 1) { if (j < s) red[j] += red[j+s]; __syncthreads(); }
  if (j < NNODE) adj[i*NNODE+j] = e / red[0];
}

// ---------------- weight repack: stride-pad rows for aligned float4 ----------------
// w5 (o,c,5) -> wp5 (o,c,8); w3 (o,c,3) -> wp3 (o,c,4)
__global__ __launch_bounds__(256) void k_rep5(const float* __restrict__ w, float* __restrict__ out) {
  int idx = blockIdx.x * 256 + threadIdx.x;
  if (idx >= 64*64*5) return;
  int oc = idx / 5, k = idx % 5;
  out[oc*8 + k] = w[idx];
}
__global__ __launch_bounds__(256) void k_rep3(const float* __restrict__ w, float* __restrict__ out) {
  int idx = blockIdx.x * 256 + threadIdx.x;
  if (idx >= 64*64*3) return;
  int oc = idx / 3, k = idx % 3;
  out[oc*4 + k] = w[idx];
}

// ---------------- fused branch: conv5(edgepad)+leaky + conv3 + tanh ----------------
// grid (170, 4, 8) block 256 = 4 waves. lane (tid&63) = output channel o,
// wave (tid>>6) = t-subtile of 16 within a 64-wide T tile.
__global__ __launch_bounds__(256) void k_branch(
    const float* __restrict__ src, int par,
    const float* __restrict__ wp5, const float* __restrict__ b5,
    const float* __restrict__ wp3, const float* __restrict__ b3,
    bf16* __restrict__ hout, float* __restrict__ h7f, float* __restrict__ Spart) {
  const int n = blockIdx.x, q = blockIdx.y, b = blockIdx.z;
  const int tid = threadIdx.x;
  const int o = tid & 63;
  const int w = tid >> 6;           // 0..3, wave-uniform
  __shared__ float xs[64][72];      // x tile: cols 0..69 (later reused as out tile)
  __shared__ float h1s[64][68];     // h1 tile: cols 0..65
  const int t0 = q * 64;
  const int base = w * 16;

  // stage x tile (edge-clamped)
  for (int i = tid; i < 64 * 70; i += 256) {
    int c = i / 70, pl = i - c * 70;
    int t = t0 + pl - 3; t = t < 0 ? 0 : (t > 255 ? 255 : t);
    size_t sb = ((size_t)b * 64 + c) * NNODE + n;
    xs[c][pl] = (par >= 0) ? src[sb * 512 + 2 * t + par] : src[sb * 256 + t];
  }
  __syncthreads();

  // ---- conv5 + leaky: lane o computes h1[o][base+tt], tt 0..15 (+2 tails on wave 3)
  {
    float acc[16];
#pragma unroll
    for (int tt = 0; tt < 16; tt++) acc[tt] = 0.f;
    float aT0 = 0.f, aT1 = 0.f;
    const float* wrow = wp5 + (size_t)o * 512;   // (o*64+c)*8
    for (int c = 0; c < 64; c++) {
      float xv[22];
      float4 v0 = *(const float4*)&xs[c][base + 0];
      float4 v1 = *(const float4*)&xs[c][base + 4];
      float4 v2 = *(const float4*)&xs[c][base + 8];
      float4 v3 = *(const float4*)&xs[c][base + 12];
      float4 v4 = *(const float4*)&xs[c][base + 16];
      xv[0]=v0.x; xv[1]=v0.y; xv[2]=v0.z; xv[3]=v0.w;
      xv[4]=v1.x; xv[5]=v1.y; xv[6]=v1.z; xv[7]=v1.w;
      xv[8]=v2.x; xv[9]=v2.y; xv[10]=v2.z; xv[11]=v2.w;
      xv[12]=v3.x; xv[13]=v3.y; xv[14]=v3.z; xv[15]=v3.w;
      xv[16]=v4.x; xv[17]=v4.y; xv[18]=v4.z; xv[19]=v4.w;
      if (w == 3) { float2 vt = *(const float2*)&xs[c][68]; xv[20]=vt.x; xv[21]=vt.y; }
      float4 wq = *(const float4*)&wrow[c*8];
      float w4 = wrow[c*8 + 4];
#pragma unroll
      for (int tt = 0; tt < 16; tt++)
        acc[tt] += wq.x*xv[tt] + wq.y*xv[tt+1] + wq.z*xv[tt+2] + wq.w*xv[tt+3] + w4*xv[tt+4];
      if (w == 3) {
        aT0 += wq.x*xv[16] + wq.y*xv[17] + wq.z*xv[18] + wq.w*xv[19] + w4*xv[20];
        aT1 += wq.x*xv[17] + wq.y*xv[18] + wq.z*xv[19] + wq.w*xv[20] + w4*xv[21];
      }
    }
    float bias = b5[o];
#pragma unroll
    for (int tt = 0; tt < 16; tt++) {
      float v = acc[tt] + bias;
      acc[tt] = v >= 0.f ? v : 0.01f * v;
    }
    *(float4*)&h1s[o][base + 0]  = make_float4(acc[0], acc[1], acc[2], acc[3]);
    *(float4*)&h1s[o][base + 4]  = make_float4(acc[4], acc[5], acc[6], acc[7]);
    *(float4*)&h1s[o][base + 8]  = make_float4(acc[8], acc[9], acc[10], acc[11]);
    *(float4*)&h1s[o][base + 12] = make_float4(acc[12], acc[13], acc[14], acc[15]);
    if (w == 3) {
      float u0 = aT0 + bias, u1 = aT1 + bias;
      u0 = u0 >= 0.f ? u0 : 0.01f * u0;
      u1 = u1 >= 0.f ? u1 : 0.01f * u1;
      *(float2*)&h1s[o][64] = make_float2(u0, u1);
    }
  }
  __syncthreads();

  // ---- conv3 + tanh -> outs (reuse xs as [64][72], cols 0..63)
  {
    float acc[16];
#pragma unroll
    for (int tt = 0; tt < 16; tt++) acc[tt] = 0.f;
    const float* wrow = wp3 + (size_t)o * 256;   // (o*64+c)*4
    for (int c = 0; c < 64; c++) {
      float xv[18];
      float4 v0 = *(const float4*)&h1s[c][base + 0];
      float4 v1 = *(const float4*)&h1s[c][base + 4];
      float4 v2 = *(const float4*)&h1s[c][base + 8];
      float4 v3 = *(const float4*)&h1s[c][base + 12];
      float2 v4 = *(const float2*)&h1s[c][base + 16];
      xv[0]=v0.x; xv[1]=v0.y; xv[2]=v0.z; xv[3]=v0.w;
      xv[4]=v1.x; xv[5]=v1.y; xv[6]=v1.z; xv[7]=v1.w;
      xv[8]=v2.x; xv[9]=v2.y; xv[10]=v2.z; xv[11]=v2.w;
      xv[12]=v3.x; xv[13]=v3.y; xv[14]=v3.z; xv[15]=v3.w;
      xv[16]=v4.x; xv[17]=v4.y;
      float4 wq = *(const float4*)&wrow[c*4];    // .w unused
#pragma unroll
      for (int tt = 0; tt < 16; tt++)
        acc[tt] += wq.x*xv[tt] + wq.y*xv[tt+1] + wq.z*xv[tt+2];
    }
    float bias = b3[o];
#pragma unroll
    for (int tt = 0; tt < 16; tt++) acc[tt] = tanhf(acc[tt] + bias);
    __syncthreads();   // all conv3 LDS reads done before overwriting xs
    *(float4*)&xs[o][base + 0]  = make_float4(acc[0], acc[1], acc[2], acc[3]);
    *(float4*)&xs[o][base + 4]  = make_float4(acc[4], acc[5], acc[6], acc[7]);
    *(float4*)&xs[o][base + 8]  = make_float4(acc[8], acc[9], acc[10], acc[11]);
    *(float4*)&xs[o][base + 12] = make_float4(acc[12], acc[13], acc[14], acc[15]);
  }
  __syncthreads();

  // ---- coalesced store: thread (ro, rq) handles o=ro, t cols rq*16..+15
  {
    const int ro = tid >> 2, rq = tid & 3;
    float4 v0 = *(const float4*)&xs[ro][rq*16 + 0];
    float4 v1 = *(const float4*)&xs[ro][rq*16 + 4];
    float4 v2 = *(const float4*)&xs[ro][rq*16 + 8];
    float4 v3 = *(const float4*)&xs[ro][rq*16 + 12];
    if (b == 7) {
      float* dst = h7f + ((size_t)ro * NNODE + n) * TT + t0 + rq*16;
      *(float4*)&dst[0] = v0; *(float4*)&dst[4] = v1;
      *(float4*)&dst[8] = v2; *(float4*)&dst[12] = v3;
      float s = v0.x+v0.y+v0.z+v0.w + v1.x+v1.y+v1.z+v1.w
              + v2.x+v2.y+v2.z+v2.w + v3.x+v3.y+v3.z+v3.w;
      s += __shfl_xor(s, 1, 4);
      s += __shfl_xor(s, 2, 4);
      if (rq == 0) Spart[(q * 64 + ro) * NNODE + n] = s;
    } else {
      bf16* dst = hout + (((size_t)b * 64 + ro) * NNODE + n) * TT + t0 + rq*16;
      uint4 p0, p1;
      p0.x = pack2(v0.x, v0.y); p0.y = pack2(v0.z, v0.w);
      p0.z = pack2(v1.x, v1.y); p0.w = pack2(v1.z, v1.w);
      p1.x = pack2(v2.x, v2.y); p1.y = pack2(v2.z, v2.w);
      p1.z = pack2(v3.x, v3.y); p1.w = pack2(v3.z, v3.w);
      *(uint4*)&dst[0] = p0;
      *(uint4*)&dst[8] = p1;
    }
  }
}

__global__ __launch_bounds__(256) void k_sred(const float* __restrict__ Spart, float* __restrict__ S) {
  int idx = blockIdx.x * 256 + threadIdx.x;
  if (idx >= CCH * NNODE) return;
  float acc = 0.f;
#pragma unroll
  for (int qq = 0; qq < 4; qq++) acc += Spart[qq * 10880 + idx];
  S[idx] = acc;
}

// ---------------- graph-gen small kernels (fp32) ----------------
__global__ __launch_bounds__(256) void k_s1(const float* __restrict__ S, const float* __restrict__ adj,
                                            float* __restrict__ S1) {
  int idx = blockIdx.x * 256 + threadIdx.x;
  if (idx >= CCH * NNODE) return;
  int c = idx / NNODE, m = idx % NNODE;
  float acc = 0.f;
  for (int n = 0; n < NNODE; n++) acc += S[c*NNODE+n] * adj[n*NNODE+m];
  S1[idx] = acc;
}

__global__ __launch_bounds__(256) void k_h0(const float* __restrict__ S, const float* __restrict__ S1,
                                            const float* __restrict__ ggw, const float* __restrict__ ggb,
                                            float* __restrict__ H0) {
  int idx = blockIdx.x * 256 + threadIdx.x;
  if (idx >= NNODE * CCH) return;
  int n = idx >> 6, o = idx & 63;
  float acc = 256.f * ggb[o];
  for (int c = 0; c < 64; c++)
    acc += ggw[o*128 + c] * S[c*NNODE+n] + ggw[o*128 + 64 + c] * S1[c*NNODE+n];
  H0[n*64 + o] = acc;
}

__global__ __launch_bounds__(256) void k_a1(const float* __restrict__ H0, const float* __restrict__ fc0w,
                                            const float* __restrict__ fc0b, float* __restrict__ A1) {
  int idx = blockIdx.x * 256 + threadIdx.x;
  if (idx >= GN) return;
  int i = idx / NNODE, j = idx % NNODE;
  float acc = fc0b[j];
  for (int o = 0; o < 64; o++) acc += H0[i*64+o] * fc0w[j*64+o];
  A1[idx] = tanhf(acc);
}

__global__ __launch_bounds__(256) void k_a2(const float* __restrict__ A1, const float* __restrict__ fc1w,
                                            const float* __restrict__ fc1b, float* __restrict__ A2) {
  int idx = blockIdx.x * 256 + threadIdx.x;
  if (idx >= NNODE * 340) return;
  int i = idx / 340, j = idx % 340;
  float acc = fc1b[j];
  for (int k = 0; k < NNODE; k++) acc += A1[i*NNODE+k] * fc1w[j*NNODE+k];
  A2[idx] = tanhf(acc);
}

__global__ __launch_bounds__(256) void k_a3(const float* __restrict__ A2, const float* __restrict__ fc2w,
                                            const float* __restrict__ fc2b, float* __restrict__ A3) {
  int idx = blockIdx.x * 256 + threadIdx.x;
  if (idx >= GN) return;
  int i = idx / NNODE, j = idx % NNODE;
  float acc = fc2b[j];
  for (int k = 0; k < 340; k++) acc += A2[i*340+k] * fc2w[j*340+k];
  A3[idx] = tanhf(acc);
}

__global__ __launch_bounds__(256) void k_dadj(const float* __restrict__ A3, const float* __restrict__ g,
                                              const float* __restrict__ adj, const float* __restrict__ a_in,
                                              float* __restrict__ dadj, float* __restrict__ out_tail) {
  int i = blockIdx.x, j = threadIdx.x;
  __shared__ float vred[256];
  __shared__ int   ired[256];
  float v = -1e30f;
  if (j < NNODE) v = A3[i*NNODE+j] + g[i*NNODE+j];
  vred[j] = v; ired[j] = j;
  __syncthreads();
  for (int s = 128; s; s >>= 1) {
    if (j < s) {
      if (vred[j+s] > vred[j]) { vred[j] = vred[j+s]; ired[j] = ired[j+s]; }
    }
    __syncthreads();
  }
  int jmax = ired[0];
  float a = a_in[0];
  if (j < NNODE) {
    float la = (j == jmax && jmax != i) ? 1.f : 0.f;
    float dv = la * a + adj[i*NNODE+j] * (1.f - a);
    dadj[i*NNODE+j] = dv;
    if (out_tail) out_tail[i*NNODE+j] = dv;
  }
}

// ---------------- hA = einsum('bcnt,nm->bcmt', h, dadj) ----------------
// grid (17, 512) ; block 256 (lane=t). Each thread: 10 m-accumulators.
__global__ __launch_bounds__(256) void k_hA(const bf16* __restrict__ h, const float* __restrict__ h7f,
                                            const float* __restrict__ dadj,
                                            bf16* __restrict__ hA, float* __restrict__ hA7f) {
  const int mt = blockIdx.x, bc = blockIdx.y;
  const int t = threadIdx.x;
  const int b = bc >> 6, c = bc & 63;
  const int m0 = mt * 10;
  __shared__ float dw[170][12];
  for (int i = t; i < 1700; i += 256) {
    int nn = i / 10, j = i - nn * 10;
    dw[nn][j] = dadj[nn * NNODE + m0 + j];
  }
  __syncthreads();
  float acc[10];
#pragma unroll
  for (int j = 0; j < 10; j++) acc[j] = 0.f;
  if (b == 7) {
    const float* hp = h7f + ((size_t)c * NNODE) * TT + t;
#pragma unroll 2
    for (int nn = 0; nn < 170; nn++) {
      float hv = hp[(size_t)nn * TT];
      float4 w0 = *(const float4*)&dw[nn][0];
      float4 w1 = *(const float4*)&dw[nn][4];
      float2 w2 = *(const float2*)&dw[nn][8];
      acc[0]+=hv*w0.x; acc[1]+=hv*w0.y; acc[2]+=hv*w0.z; acc[3]+=hv*w0.w;
      acc[4]+=hv*w1.x; acc[5]+=hv*w1.y; acc[6]+=hv*w1.z; acc[7]+=hv*w1.w;
      acc[8]+=hv*w2.x; acc[9]+=hv*w2.y;
    }
#pragma unroll
    for (int j = 0; j < 10; j++)
      hA7f[((size_t)c * NNODE + m0 + j) * TT + t] = acc[j];
  } else {
    const bf16* hp = h + ((size_t)bc * NNODE) * TT + t;
#pragma unroll 2
    for (int nn = 0; nn < 170; nn++) {
      float hv = b2f(hp[(size_t)nn * TT]);
      float4 w0 = *(const float4*)&dw[nn][0];
      float4 w1 = *(const float4*)&dw[nn][4];
      float2 w2 = *(const float2*)&dw[nn][8];
      acc[0]+=hv*w0.x; acc[1]+=hv*w0.y; acc[2]+=hv*w0.z; acc[3]+=hv*w0.w;
      acc[4]+=hv*w1.x; acc[5]+=hv*w1.y; acc[6]+=hv*w1.z; acc[7]+=hv*w1.w;
      acc[8]+=hv*w2.x; acc[9]+=hv*w2.y;
    }
#pragma unroll
    for (int j = 0; j < 10; j++)
      hA[((size_t)bc * NNODE + m0 + j) * TT + t] = f2b(acc[j]);
  }
}

// ---------------- channel mix + residual + per-step epilogue ----------------
// grid (170, 8) block 256 (lane=t). 4 passes of 16 o-accumulators.
// epi: 1: outo = x_odd*tanh(v); 2: oute = x_even*tanh(v); 3: outo -= v; 4: oute += v
__global__ __launch_bounds__(256) void k_mix(const bf16* __restrict__ h, const bf16* __restrict__ hA,
                                             const float* __restrict__ h7f, const float* __restrict__ hA7f,
                                             const float* __restrict__ dcw, const float* __restrict__ dcb,
                                             const float* __restrict__ x,
                                             float* __restrict__ oute, float* __restrict__ outo, int epi) {
  const int n = blockIdx.x, b = blockIdx.y;
  const int t = threadIdx.x;
  __shared__ float wT[128][68];   // wT[cf][o] = dcw[o*128+cf]
  for (int i = t; i < 8192; i += 256) {
    int o_ = i >> 7, cf_ = i & 127;
    wT[cf_][o_] = dcw[i];
  }
  __syncthreads();
  const bool b7 = (b == 7);
  for (int p = 0; p < 4; p++) {
    float acc[16];
#pragma unroll
    for (int oo = 0; oo < 16; oo++) acc[oo] = 0.f;
    for (int cc = 0; cc < 64; cc++) {
      float hv, hav;
      if (b7) {
        size_t off = ((size_t)cc * NNODE + n) * TT + t;
        hv = h7f[off]; hav = hA7f[off];
      } else {
        size_t off = (((size_t)b * 64 + cc) * NNODE + n) * TT + t;
        hv = b2f(h[off]); hav = b2f(hA[off]);
      }
      float4 wh0 = *(const float4*)&wT[cc][p*16 + 0];
      float4 wh1 = *(const float4*)&wT[cc][p*16 + 4];
      float4 wh2 = *(const float4*)&wT[cc][p*16 + 8];
      float4 wh3 = *(const float4*)&wT[cc][p*16 + 12];
      float4 wa0 = *(const float4*)&wT[64+cc][p*16 + 0];
      float4 wa1 = *(const float4*)&wT[64+cc][p*16 + 4];
      float4 wa2 = *(const float4*)&wT[64+cc][p*16 + 8];
      float4 wa3 = *(const float4*)&wT[64+cc][p*16 + 12];
      acc[0]+=wh0.x*hv+wa0.x*hav;  acc[1]+=wh0.y*hv+wa0.y*hav;
      acc[2]+=wh0.z*hv+wa0.z*hav;  acc[3]+=wh0.w*hv+wa0.w*hav;
      acc[4]+=wh1.x*hv+wa1.x*hav;  acc[5]+=wh1.y*hv+wa1.y*hav;
      acc[6]+=wh1.z*hv+wa1.z*hav;  acc[7]+=wh1.w*hv+wa1.w*hav;
      acc[8]+=wh2.x*hv+wa2.x*hav;  acc[9]+=wh2.y*hv+wa2.y*hav;
      acc[10]+=wh2.z*hv+wa2.z*hav; acc[11]+=wh2.w*hv+wa2.w*hav;
      acc[12]+=wh3.x*hv+wa3.x*hav; acc[13]+=wh3.y*hv+wa3.y*hav;
      acc[14]+=wh3.z*hv+wa3.z*hav; acc[15]+=wh3.w*hv+wa3.w*hav;
    }
#pragma unroll
    for (int oo = 0; oo < 16; oo++) {
      int o = p * 16 + oo;
      size_t oidx = (((size_t)b * 64 + o) * NNODE + n) * TT + t;
      float hres = b7 ? h7f[((size_t)o * NNODE + n) * TT + t] : b2f(h[oidx]);
      float v = acc[oo] + hres + dcb[o];
      if (epi == 1) {
        outo[oidx] = x[(((size_t)b * 64 + o) * NNODE + n) * 512 + 2*t + 1] * tanhf(v);
      } else if (epi == 2) {
        oute[oidx] = x[(((size_t)b * 64 + o) * NNODE + n) * 512 + 2*t] * tanhf(v);
      } else if (epi == 3) {
        outo[oidx] -= v;
      } else {
        oute[oidx] += v;
      }
    }
  }
}

// ---------------- host ----------------
extern "C" void kernel_launch(void* const* d_in, const int* in_sizes, int n_in,
                              void* d_out, int out_size, void* d_ws, size_t ws_size,
                              hipStream_t stream) {
  const float* x    = (const float*)d_in[0];
  const float* nv1  = (const float*)d_in[1];
  const float* nv2  = (const float*)d_in[2];
  const float* a_in = (const float*)d_in[3];
  const float *w5[4], *b5[4], *w3[4], *b3[4];
  for (int s = 0; s < 4; s++) {
    w5[s] = (const float*)d_in[4 + 4*s];
    b5[s] = (const float*)d_in[5 + 4*s];
    w3[s] = (const float*)d_in[6 + 4*s];
    b3[s] = (const float*)d_in[7 + 4*s];
  }
  const float* ggw  = (const float*)d_in[20];
  const float* ggb  = (const float*)d_in[21];
  const float* fc0w = (const float*)d_in[22];
  const float* fc0b = (const float*)d_in[23];
  const float* fc1w = (const float*)d_in[24];
  const float* fc1b = (const float*)d_in[25];
  const float* fc2w = (const float*)d_in[26];
  const float* fc2b = (const float*)d_in[27];
  const float* dcw  = (const float*)d_in[28];
  const float* dcb  = (const float*)d_in[29];

  char* p = (char*)d_ws;
  size_t used = 0;
  auto alloc = [&](size_t bytes) -> char* {
    char* r = p + used;
    used += (bytes + 255) & ~(size_t)255;
    return r;
  };
  float* adjW   = (float*)alloc(GN*4);
  float* dadjW  = (float*)alloc(GN*4);
  float* gW     = (float*)alloc(4*GN*4);
  unsigned* keys= (unsigned*)alloc(8*4);
  float* Sa     = (float*)alloc(CCH*NNODE*4);
  float* Sb     = (float*)alloc(CCH*NNODE*4);
  float* Spart  = (float*)alloc(4*CCH*NNODE*4);
  float* S1     = (float*)alloc(CCH*NNODE*4);
  float* H0     = (float*)alloc(NNODE*CCH*4);
  float* A1     = (float*)alloc(GN*4);
  float* A2     = (float*)alloc(NNODE*340*4);
  float* A3     = (float*)alloc(GN*4);
  float* wp5[4]; float* wp3[4];
  for (int s = 0; s < 4; s++) { wp5[s] = (float*)alloc(64*64*8*4); wp3[s] = (float*)alloc(64*64*4*4); }
  bf16* H1      = (bf16*)alloc(HSZ*2);
  bf16* H2      = (bf16*)alloc(HSZ*2);
  bf16* HA      = (bf16*)alloc(HSZ*2);
  float* h7fA   = (float*)alloc(H7SZ*4);
  float* h7fB   = (float*)alloc(H7SZ*4);
  float* hA7f   = (float*)alloc(H7SZ*4);
  if (used > ws_size) return;  // signature: output stays zero

  float* oute = (float*)d_out;
  float* outo = oute + HSZ;
  float* tail = oute + 2*HSZ;

  dim3 bgrid(NNODE, 4, BBATCH);
  dim3 agrid(17, 512);
  dim3 mgrid(NNODE, BBATCH);

  for (int s = 0; s < 4; s++) {
    k_rep5<<<80, 256, 0, stream>>>(w5[s], wp5[s]);
    k_rep3<<<48, 256, 0, stream>>>(w3[s], wp3[s]);
  }
  k_adj<<<NNODE, 256, 0, stream>>>(nv1, nv2, adjW);
  k_keys<<<1, 64, 0, stream>>>(keys);
  k_gumbel<<<(4*GN + 255)/256, 256, 0, stream>>>(keys, gW);

  auto graph_pipe = [&](const float* S, const float* gstep, float* tailp) {
    k_s1<<<43, 256, 0, stream>>>(S, adjW, S1);
    k_h0<<<43, 256, 0, stream>>>(S, S1, ggw, ggb, H0);
    k_a1<<<113, 256, 0, stream>>>(H0, fc0w, fc0b, A1);
    k_a2<<<226, 256, 0, stream>>>(A1, fc1w, fc1b, A2);
    k_a3<<<113, 256, 0, stream>>>(A2, fc2w, fc2b, A3);
    k_dadj<<<NNODE, 256, 0, stream>>>(A3, gstep, adjW, a_in, dadjW, tailp);
  };

  // step 1: branch(xe) -> x1 ; d = xo*tanh(x1) -> outo
  k_branch<<<bgrid, 256, 0, stream>>>(x, 0, wp5[0], b5[0], wp3[0], b3[0], H1, h7fA, Spart);
  k_sred<<<43, 256, 0, stream>>>(Spart, Sa);
  graph_pipe(Sa, gW, nullptr);
  k_hA<<<agrid, 256, 0, stream>>>(H1, h7fA, dadjW, HA, hA7f);
  k_mix<<<mgrid, 256, 0, stream>>>(H1, HA, h7fA, hA7f, dcw, dcb, x, oute, outo, 1);

  // step 2: branch(xo) -> x2 ; c = xe*tanh(x2) -> oute
  k_branch<<<bgrid, 256, 0, stream>>>(x, 1, wp5[1], b5[1], wp3[1], b3[1], H1, h7fA, Spart);
  k_sred<<<43, 256, 0, stream>>>(Spart, Sa);
  graph_pipe(Sa, gW + GN, nullptr);
  k_hA<<<agrid, 256, 0, stream>>>(H1, h7fA, dadjW, HA, hA7f);
  k_mix<<<mgrid, 256, 0, stream>>>(H1, HA, h7fA, hA7f, dcw, dcb, x, oute, outo, 2);

  // steps 3 & 4: run both branches BEFORE either epilogue overwrites d_out
  k_branch<<<bgrid, 256, 0, stream>>>(oute, -1, wp5[2], b5[2], wp3[2], b3[2], H1, h7fA, Spart);
  k_sred<<<43, 256, 0, stream>>>(Spart, Sa);
  k_branch<<<bgrid, 256, 0, stream>>>(outo, -1, wp5[3], b5[3], wp3[3], b3[3], H2, h7fB, Spart);
  k_sred<<<43, 256, 0, stream>>>(Spart, Sb);

  // step 3 rest: outo = d - x3
  graph_pipe(Sa, gW + 2*GN, nullptr);
  k_hA<<<agrid, 256, 0, stream>>>(H1, h7fA, dadjW, HA, hA7f);
  k_mix<<<mgrid, 256, 0, stream>>>(H1, HA, h7fA, hA7f, dcw, dcb, x, oute, outo, 3);

  // step 4 rest: oute = c + x4 ; dadj -> tail
  graph_pipe(Sb, gW + 3*GN, tail);
  k_hA<<<agrid, 256, 0, stream>>>(H2, h7fB, dadjW, HA, hA7f);
  k_mix<<<mgrid, 256, 0, stream>>>(H2, HA, h7fB, hA7f, dcw, dcb, x, oute, outo, 4);

  (void)in_sizes; (void)n_in; (void)out_size;
}

// Round 4
// 4055.846 us; speedup vs baseline: 3.9708x; 1.0698x over previous
//
#include <hip/hip_runtime.h>
#include <hip/hip_bf16.h>
#include <cstdint>
#include <cstddef>

using bf16 = __hip_bfloat16;

static constexpr int BBATCH = 8, CCH = 64, NNODE = 170, TT = 256;
static constexpr size_t HSZ  = (size_t)BBATCH * CCH * NNODE * TT;  // 22282240
static constexpr size_t H7SZ = (size_t)CCH * NNODE * TT;           // 2785280
static constexpr int GN = NNODE * NNODE;                           // 28900

__device__ __forceinline__ float b2f(bf16 v) { return __bfloat162float(v); }
__device__ __forceinline__ bf16  f2b(float v) { return __float2bfloat16(v); }

union BfU { bf16 h; unsigned short s; };
__device__ __forceinline__ unsigned pack2(float a, float b) {
  BfU x, y; x.h = f2b(a); y.h = f2b(b);
  return ((unsigned)y.s << 16) | x.s;
}

// ---------------- threefry2x32 (JAX-compatible, partitionable) ----------------
__device__ __forceinline__ unsigned rotl32(unsigned v, int d) { return (v << d) | (v >> (32 - d)); }

__device__ void threefry2x32(unsigned k0, unsigned k1, unsigned x0, unsigned x1,
                             unsigned& y0, unsigned& y1) {
  unsigned ks0 = k0, ks1 = k1, ks2 = k0 ^ k1 ^ 0x1BD11BDAu;
  x0 += ks0; x1 += ks1;
  const int ra[4] = {13, 15, 26, 6};
  const int rb[4] = {17, 29, 16, 24};
#pragma unroll
  for (int r = 0; r < 4; r++) { x0 += x1; x1 = rotl32(x1, ra[r]); x1 ^= x0; }
  x0 += ks1; x1 += ks2 + 1u;
#pragma unroll
  for (int r = 0; r < 4; r++) { x0 += x1; x1 = rotl32(x1, rb[r]); x1 ^= x0; }
  x0 += ks2; x1 += ks0 + 2u;
#pragma unroll
  for (int r = 0; r < 4; r++) { x0 += x1; x1 = rotl32(x1, ra[r]); x1 ^= x0; }
  x0 += ks0; x1 += ks1 + 3u;
#pragma unroll
  for (int r = 0; r < 4; r++) { x0 += x1; x1 = rotl32(x1, rb[r]); x1 ^= x0; }
  x0 += ks1; x1 += ks2 + 4u;
#pragma unroll
  for (int r = 0; r < 4; r++) { x0 += x1; x1 = rotl32(x1, ra[r]); x1 ^= x0; }
  x0 += ks2; x1 += ks0 + 5u;
  y0 = x0; y1 = x1;
}

__global__ void k_keys(unsigned* keys) {
  int j = threadIdx.x;
  if (j < 4) {
    unsigned y0, y1;
    threefry2x32(0u, 42u, 0u, (unsigned)j, y0, y1);
    keys[2*j] = y0; keys[2*j+1] = y1;
  }
}

__global__ __launch_bounds__(256) void k_gumbel(const unsigned* __restrict__ keys,
                                                float* __restrict__ g) {
  int idx = blockIdx.x * 256 + threadIdx.x;
  if (idx >= 4 * GN) return;
  int w = idx / GN, i = idx % GN;
  unsigned y0, y1;
  threefry2x32(keys[2*w], keys[2*w+1], 0u, (unsigned)i, y0, y1);
  unsigned bits = y0 ^ y1;
  unsigned fb = (bits >> 9) | 0x3f800000u;
  float u = __uint_as_float(fb) - 1.0f;
  g[idx] = -logf(-logf(u + 1e-20f) + 1e-20f);
}

// ---------------- adj = softmax(relu(nv1@nv2), axis=1) ----------------
__global__ __launch_bounds__(256) void k_adj(const float* __restrict__ nv1,
                                             const float* __restrict__ nv2,
                                             float* __restrict__ adj) {
  int i = blockIdx.x, j = threadIdx.x;
  __shared__ float red[256];
  float val = 0.f, r = -1e30f;
  if (j < NNODE) {
    float acc = 0.f;
    for (int k = 0; k < 10; k++) acc += nv1[i*10+k] * nv2[k*NNODE+j];
    val = acc > 0.f ? acc : 0.f;
    r = val;
  }
  red[j] = r; __syncthreads();
  for (int s = 128; s; s >>= 1) { if (j < s) red[j] = fmaxf(red[j], red[j+s]); __syncthreads(); }
  float m = red[0]; __syncthreads();
  float e = (j < NNODE) ? expf(val - m) : 0.f;
  red[j] = e; __syncthreads();
  for (int s = 128; s; s >>= 1) { if (j < s) red[j] += red[j+s]; __syncthreads(); }
  if (j < NNODE) adj[i*NNODE+j] = e / red[0];
}

// ---------------- weight repacks ----------------
// w5 (o,c,5) -> wc5 (c,o,5)   [scalar path]
__global__ __launch_bounds__(256) void k_rep5c(const float* __restrict__ w, float* __restrict__ out) {
  int idx = blockIdx.x * 256 + threadIdx.x;
  if (idx >= 64*64*5) return;
  int oc = idx / 5, k = idx - oc * 5;
  int o = oc >> 6, c = oc & 63;
  out[(c*64 + o)*5 + k] = w[idx];
}
// w5 (o,c,5) -> wo5 (o,c,8) padded  [halo-wave path]
__global__ __launch_bounds__(256) void k_rep5o(const float* __restrict__ w, float* __restrict__ out) {
  int idx = blockIdx.x * 256 + threadIdx.x;
  if (idx >= 64*64*5) return;
  int oc = idx / 5, k = idx - oc * 5;
  out[oc*8 + k] = w[idx];
}
// w3 (o,c,3) -> wc3 (c,o,3)
__global__ __launch_bounds__(256) void k_rep3c(const float* __restrict__ w, float* __restrict__ out) {
  int idx = blockIdx.x * 256 + threadIdx.x;
  if (idx >= 64*64*3) return;
  int oc = idx / 3, k = idx - oc * 3;
  int o = oc >> 6, c = oc & 63;
  out[(c*64 + o)*3 + k] = w[idx];
}

// ---------------- fused branch: conv5(edgepad)+leaky + conv3 + tanh ----------------
// grid (170, 4, 8), block 320 = 5 waves. Waves 0-3: lane = t (64-wide tile),
// wave = 16-o group, weights via wave-uniform (scalar) loads. Wave 4: halo cols 64,65.
__global__ __launch_bounds__(320) void k_branch(
    const float* __restrict__ src, int par,
    const float* __restrict__ wc5, const float* __restrict__ wo5,
    const float* __restrict__ b5,
    const float* __restrict__ wc3, const float* __restrict__ b3,
    bf16* __restrict__ hout, float* __restrict__ h7f, float* __restrict__ Spart) {
  const int n = blockIdx.x, q = blockIdx.y, b = blockIdx.z;
  const int tid = threadIdx.x;
  const int lane = tid & 63;
  const int w = __builtin_amdgcn_readfirstlane(tid >> 6);
  __shared__ float xs[64][72];     // x tile cols 0..69; reused as out tile
  __shared__ float h1s[64][68];    // h1 cols 0..65
  const int t0 = q * 64;

  for (int i = tid; i < 64 * 70; i += 320) {
    int c = i / 70, pl = i - c * 70;
    int t = t0 + pl - 3; t = t < 0 ? 0 : (t > 255 ? 255 : t);
    size_t sb = ((size_t)b * 64 + c) * NNODE + n;
    xs[c][pl] = (par >= 0) ? src[sb * 512 + 2 * t + par] : src[sb * 256 + t];
  }
  __syncthreads();

  // ---- conv5 + leaky
  if (w < 4) {
    const int o0 = w * 16;
    float acc[16];
#pragma unroll
    for (int oo = 0; oo < 16; oo++) acc[oo] = 0.f;
    for (int c = 0; c < 64; c++) {
      float x0 = xs[c][lane], x1 = xs[c][lane+1], x2 = xs[c][lane+2],
            x3 = xs[c][lane+3], x4 = xs[c][lane+4];
      const float* wr = &wc5[(c * 64 + o0) * 5];
#pragma unroll
      for (int oo = 0; oo < 16; oo++)
        acc[oo] += wr[oo*5+0]*x0 + wr[oo*5+1]*x1 + wr[oo*5+2]*x2
                 + wr[oo*5+3]*x3 + wr[oo*5+4]*x4;
    }
#pragma unroll
    for (int oo = 0; oo < 16; oo++) {
      float v = acc[oo] + b5[o0+oo];
      h1s[o0+oo][lane] = v >= 0.f ? v : 0.01f * v;
    }
  } else {
    // halo positions 64,65; o = lane (per-lane weight rows, tiny fraction of work)
    float a0 = 0.f, a1 = 0.f;
    const float* wrow = wo5 + (size_t)lane * 512;
    for (int c = 0; c < 64; c++) {
      float y0 = xs[c][64], y1 = xs[c][65], y2 = xs[c][66],
            y3 = xs[c][67], y4 = xs[c][68], y5 = xs[c][69];
      float4 wq = *(const float4*)&wrow[c*8];
      float w4 = wrow[c*8+4];
      a0 += wq.x*y0 + wq.y*y1 + wq.z*y2 + wq.w*y3 + w4*y4;
      a1 += wq.x*y1 + wq.y*y2 + wq.z*y3 + wq.w*y4 + w4*y5;
    }
    float bias = b5[lane];
    a0 += bias; a1 += bias;
    h1s[lane][64] = a0 >= 0.f ? a0 : 0.01f * a0;
    h1s[lane][65] = a1 >= 0.f ? a1 : 0.01f * a1;
  }
  __syncthreads();

  // ---- conv3 + tanh -> write into xs (xs reads all completed before prev barrier)
  if (w < 4) {
    const int o0 = w * 16;
    float acc[16];
#pragma unroll
    for (int oo = 0; oo < 16; oo++) acc[oo] = 0.f;
    for (int c = 0; c < 64; c++) {
      float x0 = h1s[c][lane], x1 = h1s[c][lane+1], x2 = h1s[c][lane+2];
      const float* wr = &wc3[(c * 64 + o0) * 3];
#pragma unroll
      for (int oo = 0; oo < 16; oo++)
        acc[oo] += wr[oo*3+0]*x0 + wr[oo*3+1]*x1 + wr[oo*3+2]*x2;
    }
#pragma unroll
    for (int oo = 0; oo < 16; oo++)
      xs[o0+oo][lane] = tanhf(acc[oo] + b3[o0+oo]);
  }
  __syncthreads();

  // ---- coalesced store (first 256 threads)
  if (tid < 256) {
    const int ro = tid >> 2, rq = tid & 3;
    float4 v0 = *(const float4*)&xs[ro][rq*16 + 0];
    float4 v1 = *(const float4*)&xs[ro][rq*16 + 4];
    float4 v2 = *(const float4*)&xs[ro][rq*16 + 8];
    float4 v3 = *(const float4*)&xs[ro][rq*16 + 12];
    if (b == 7) {
      float* dst = h7f + ((size_t)ro * NNODE + n) * TT + t0 + rq*16;
      *(float4*)&dst[0] = v0; *(float4*)&dst[4] = v1;
      *(float4*)&dst[8] = v2; *(float4*)&dst[12] = v3;
      float s = v0.x+v0.y+v0.z+v0.w + v1.x+v1.y+v1.z+v1.w
              + v2.x+v2.y+v2.z+v2.w + v3.x+v3.y+v3.z+v3.w;
      s += __shfl_xor(s, 1, 4);
      s += __shfl_xor(s, 2, 4);
      if (rq == 0) Spart[(q * 64 + ro) * NNODE + n] = s;
    } else {
      bf16* dst = hout + (((size_t)b * 64 + ro) * NNODE + n) * TT + t0 + rq*16;
      uint4 p0, p1;
      p0.x = pack2(v0.x, v0.y); p0.y = pack2(v0.z, v0.w);
      p0.z = pack2(v1.x, v1.y); p0.w = pack2(v1.z, v1.w);
      p1.x = pack2(v2.x, v2.y); p1.y = pack2(v2.z, v2.w);
      p1.z = pack2(v3.x, v3.y); p1.w = pack2(v3.z, v3.w);
      *(uint4*)&dst[0] = p0;
      *(uint4*)&dst[8] = p1;
    }
  }
}

// ---------------- ST[n][c] = sum_q Spart ----------------
__global__ __launch_bounds__(256) void k_sredT(const float* __restrict__ Spart, float* __restrict__ ST) {
  int idx = blockIdx.x * 256 + threadIdx.x;
  if (idx >= CCH * NNODE) return;
  int nn = idx >> 6, c = idx & 63;
  float acc = 0.f;
#pragma unroll
  for (int qq = 0; qq < 4; qq++) acc += Spart[(qq * 64 + c) * NNODE + nn];
  ST[idx] = acc;
}

// ---------------- fused S1 + H0 (block per node n, 64 threads) ----------------
__global__ __launch_bounds__(64) void k_s1h0(const float* __restrict__ ST, const float* __restrict__ adj,
                                             const float* __restrict__ ggw, const float* __restrict__ ggb,
                                             float* __restrict__ H0) {
  const int n = blockIdx.x;
  const int tid = threadIdx.x;
  __shared__ float s1[64], sc[64];
  {
    const int c = tid;
    float acc = 0.f;
    for (int nn = 0; nn < NNODE; nn++) acc += ST[nn*64 + c] * adj[nn*NNODE + n];
    s1[c] = acc;
    sc[c] = ST[n*64 + c];
  }
  __syncthreads();
  {
    const int o = tid;
    float acc = 256.f * ggb[o];
    for (int c = 0; c < 64; c++)
      acc += ggw[o*128 + c] * sc[c] + ggw[o*128 + 64 + c] * s1[c];
    H0[n*64 + o] = acc;
  }
}

// ---------------- fused fc0+fc1+fc2 + gumbel-argmax + dadj (block per row i) ----------------
__global__ __launch_bounds__(256) void k_fc(const float* __restrict__ H0,
    const float* __restrict__ fc0w, const float* __restrict__ fc0b,
    const float* __restrict__ fc1w, const float* __restrict__ fc1b,
    const float* __restrict__ fc2w, const float* __restrict__ fc2b,
    const float* __restrict__ g, const float* __restrict__ adj,
    const float* __restrict__ a_in,
    float* __restrict__ dadj, float* __restrict__ out_tail) {
  const int i = blockIdx.x;
  const int tid = threadIdx.x;
  __shared__ float h0r[64];
  __shared__ float a1r[NNODE];
  __shared__ float a2r[340];
  __shared__ float vred[256];
  __shared__ int ired[256];
  if (tid < 64) h0r[tid] = H0[i*64 + tid];
  __syncthreads();
  if (tid < NNODE) {
    float acc = fc0b[tid];
    for (int o = 0; o < 64; o++) acc += h0r[o] * fc0w[tid*64 + o];
    a1r[tid] = tanhf(acc);
  }
  __syncthreads();
  for (int j = tid; j < 340; j += 256) {
    float acc = fc1b[j];
    for (int k = 0; k < NNODE; k++) acc += a1r[k] * fc1w[j*NNODE + k];
    a2r[j] = tanhf(acc);
  }
  __syncthreads();
  float v = -1e30f;
  if (tid < NNODE) {
    float acc = fc2b[tid];
    for (int k = 0; k < 340; k++) acc += a2r[k] * fc2w[tid*340 + k];
    v = tanhf(acc) + g[i*NNODE + tid];
  }
  vred[tid] = v; ired[tid] = tid;
  __syncthreads();
  for (int s = 128; s; s >>= 1) {
    if (tid < s) {
      if (vred[tid+s] > vred[tid]) { vred[tid] = vred[tid+s]; ired[tid] = ired[tid+s]; }
    }
    __syncthreads();
  }
  int jmax = ired[0];
  float a = a_in[0];
  if (tid < NNODE) {
    float la = (tid == jmax && jmax != i) ? 1.f : 0.f;
    float dv = la * a + adj[i*NNODE + tid] * (1.f - a);
    dadj[i*NNODE + tid] = dv;
    if (out_tail) out_tail[i*NNODE + tid] = dv;
  }
}

// ---------------- hA = einsum('bcnt,nm->bcmt', h, dadj) ----------------
// grid (512 bc, 8 tq), block 256. Stage h tile [170][32] in LDS (fp32);
// lane = m (3 groups of 64), wave = 8-t subgroup; coalesced dadj loads;
// transpose back through LDS for coalesced stores.
__global__ __launch_bounds__(256) void k_hA(const bf16* __restrict__ h, const float* __restrict__ h7f,
                                            const float* __restrict__ dadj,
                                            bf16* __restrict__ hA, float* __restrict__ hA7f) {
  const int bc = blockIdx.x, tq = blockIdx.y;
  const int b = bc >> 6;
  const int t0 = tq * 32;
  const int tid = threadIdx.x;
  const int lane = tid & 63;
  const int w = __builtin_amdgcn_readfirstlane(tid >> 6);
  __shared__ float hs[170][33];
  if (b == 7) {
    const int c = bc & 63;
    for (int i = tid; i < 170*32; i += 256) {
      int nn = i >> 5, tl = i & 31;
      hs[nn][tl] = h7f[((size_t)c * NNODE + nn) * TT + t0 + tl];
    }
  } else {
    for (int i = tid; i < 170*32; i += 256) {
      int nn = i >> 5, tl = i & 31;
      hs[nn][tl] = b2f(h[((size_t)bc * NNODE + nn) * TT + t0 + tl]);
    }
  }
  __syncthreads();
  float acc0[8], acc1[8], acc2[8];
#pragma unroll
  for (int tt = 0; tt < 8; tt++) { acc0[tt] = 0.f; acc1[tt] = 0.f; acc2[tt] = 0.f; }
  const int toff = w * 8;
  for (int nn = 0; nn < NNODE; nn++) {
    float hv[8];
#pragma unroll
    for (int tt = 0; tt < 8; tt++) hv[tt] = hs[nn][toff + tt];
    const float* dr = &dadj[nn * NNODE];
    float w0 = dr[lane];
    float w1 = dr[64 + lane];
    float w2 = (lane < 42) ? dr[128 + lane] : 0.f;
#pragma unroll
    for (int tt = 0; tt < 8; tt++) {
      acc0[tt] += w0 * hv[tt];
      acc1[tt] += w1 * hv[tt];
      acc2[tt] += w2 * hv[tt];
    }
  }
  __syncthreads();   // hs reads done; reuse as transpose buffer
#pragma unroll
  for (int tt = 0; tt < 8; tt++) {
    hs[lane][toff + tt] = acc0[tt];
    hs[64 + lane][toff + tt] = acc1[tt];
    if (lane < 42) hs[128 + lane][toff + tt] = acc2[tt];
  }
  __syncthreads();
  if (tid < NNODE) {
    if (b == 7) {
      const int c = bc & 63;
      float* dst = hA7f + ((size_t)c * NNODE + tid) * TT + t0;
#pragma unroll
      for (int j = 0; j < 8; j++)
        *(float4*)&dst[j*4] = make_float4(hs[tid][j*4], hs[tid][j*4+1], hs[tid][j*4+2], hs[tid][j*4+3]);
    } else {
      bf16* dst = hA + ((size_t)bc * NNODE + tid) * TT + t0;
      unsigned u[16];
#pragma unroll
      for (int j = 0; j < 16; j++) u[j] = pack2(hs[tid][2*j], hs[tid][2*j+1]);
      *(uint4*)&dst[0]  = make_uint4(u[0],u[1],u[2],u[3]);
      *(uint4*)&dst[8]  = make_uint4(u[4],u[5],u[6],u[7]);
      *(uint4*)&dst[16] = make_uint4(u[8],u[9],u[10],u[11]);
      *(uint4*)&dst[24] = make_uint4(u[12],u[13],u[14],u[15]);
    }
  }
}

// ---------------- channel mix + residual + per-step epilogue (single pass) ----------------
// grid (170, 8), block 256 (thread = t). 64 accumulators; weights broadcast from LDS.
// epi: 1: outo = x_odd*tanh(v); 2: oute = x_even*tanh(v); 3: outo -= v; 4: oute += v
__global__ __launch_bounds__(256) void k_mix(const bf16* __restrict__ h, const bf16* __restrict__ hA,
                                             const float* __restrict__ h7f, const float* __restrict__ hA7f,
                                             const float* __restrict__ dcw, const float* __restrict__ dcb,
                                             const float* __restrict__ x,
                                             float* __restrict__ oute, float* __restrict__ outo, int epi) {
  const int n = blockIdx.x, b = blockIdx.y;
  const int t = threadIdx.x;
  __shared__ float wT[128][64];   // wT[cf][o]
  for (int i = t; i < 8192; i += 256) {
    int o_ = i >> 7, cf_ = i & 127;
    wT[cf_][o_] = dcw[i];
  }
  __syncthreads();
  const bool b7 = (b == 7);
  float acc[64];
#pragma unroll
  for (int oo = 0; oo < 64; oo++) acc[oo] = 0.f;
  for (int cc = 0; cc < 64; cc++) {
    float hv, hav;
    if (b7) {
      size_t off = ((size_t)cc * NNODE + n) * TT + t;
      hv = h7f[off]; hav = hA7f[off];
    } else {
      size_t off = (((size_t)b * 64 + cc) * NNODE + n) * TT + t;
      hv = b2f(h[off]); hav = b2f(hA[off]);
    }
#pragma unroll
    for (int oo = 0; oo < 64; oo++)
      acc[oo] += wT[cc][oo] * hv + wT[64+cc][oo] * hav;
  }
#pragma unroll
  for (int oo = 0; oo < 64; oo++) {
    size_t oidx = (((size_t)b * 64 + oo) * NNODE + n) * TT + t;
    float hres = b7 ? h7f[((size_t)oo * NNODE + n) * TT + t] : b2f(h[oidx]);
    float v = acc[oo] + hres + dcb[oo];
    if (epi == 1) {
      outo[oidx] = x[(((size_t)b*64 + oo) * NNODE + n) * 512 + 2*t + 1] * tanhf(v);
    } else if (epi == 2) {
      oute[oidx] = x[(((size_t)b*64 + oo) * NNODE + n) * 512 + 2*t] * tanhf(v);
    } else if (epi == 3) {
      outo[oidx] -= v;
    } else {
      oute[oidx] += v;
    }
  }
}

// ---------------- host ----------------
extern "C" void kernel_launch(void* const* d_in, const int* in_sizes, int n_in,
                              void* d_out, int out_size, void* d_ws, size_t ws_size,
                              hipStream_t stream) {
  const float* x    = (const float*)d_in[0];
  const float* nv1  = (const float*)d_in[1];
  const float* nv2  = (const float*)d_in[2];
  const float* a_in = (const float*)d_in[3];
  const float *w5[4], *b5[4], *w3[4], *b3[4];
  for (int s = 0; s < 4; s++) {
    w5[s] = (const float*)d_in[4 + 4*s];
    b5[s] = (const float*)d_in[5 + 4*s];
    w3[s] = (const float*)d_in[6 + 4*s];
    b3[s] = (const float*)d_in[7 + 4*s];
  }
  const float* ggw  = (const float*)d_in[20];
  const float* ggb  = (const float*)d_in[21];
  const float* fc0w = (const float*)d_in[22];
  const float* fc0b = (const float*)d_in[23];
  const float* fc1w = (const float*)d_in[24];
  const float* fc1b = (const float*)d_in[25];
  const float* fc2w = (const float*)d_in[26];
  const float* fc2b = (const float*)d_in[27];
  const float* dcw  = (const float*)d_in[28];
  const float* dcb  = (const float*)d_in[29];

  char* p = (char*)d_ws;
  size_t used = 0;
  auto alloc = [&](size_t bytes) -> char* {
    char* r = p + used;
    used += (bytes + 255) & ~(size_t)255;
    return r;
  };
  float* adjW   = (float*)alloc(GN*4);
  float* dadjW  = (float*)alloc(GN*4);
  float* gW     = (float*)alloc(4*GN*4);
  unsigned* keys= (unsigned*)alloc(8*4);
  float* STa    = (float*)alloc(CCH*NNODE*4);
  float* STb    = (float*)alloc(CCH*NNODE*4);
  float* Spart  = (float*)alloc(4*CCH*NNODE*4);
  float* H0     = (float*)alloc(NNODE*CCH*4);
  float* wc5[4]; float* wo5[4]; float* wc3[4];
  for (int s = 0; s < 4; s++) {
    wc5[s] = (float*)alloc(64*64*5*4);
    wo5[s] = (float*)alloc(64*64*8*4);
    wc3[s] = (float*)alloc(64*64*3*4);
  }
  bf16* H1      = (bf16*)alloc(HSZ*2);
  bf16* H2      = (bf16*)alloc(HSZ*2);
  bf16* HA      = (bf16*)alloc(HSZ*2);
  float* h7fA   = (float*)alloc(H7SZ*4);
  float* h7fB   = (float*)alloc(H7SZ*4);
  float* hA7f   = (float*)alloc(H7SZ*4);
  if (used > ws_size) return;  // signature: output stays zero

  float* oute = (float*)d_out;
  float* outo = oute + HSZ;
  float* tail = oute + 2*HSZ;

  dim3 bgrid(NNODE, 4, BBATCH);
  dim3 agrid(512, 8);
  dim3 mgrid(NNODE, BBATCH);

  for (int s = 0; s < 4; s++) {
    k_rep5c<<<80, 256, 0, stream>>>(w5[s], wc5[s]);
    k_rep5o<<<80, 256, 0, stream>>>(w5[s], wo5[s]);
    k_rep3c<<<48, 256, 0, stream>>>(w3[s], wc3[s]);
  }
  k_adj<<<NNODE, 256, 0, stream>>>(nv1, nv2, adjW);
  k_keys<<<1, 64, 0, stream>>>(keys);
  k_gumbel<<<(4*GN + 255)/256, 256, 0, stream>>>(keys, gW);

  auto graph_pipe = [&](float* ST, const float* gstep, float* tailp) {
    k_sredT<<<43, 256, 0, stream>>>(Spart, ST);
    k_s1h0<<<NNODE, 64, 0, stream>>>(ST, adjW, ggw, ggb, H0);
    k_fc<<<NNODE, 256, 0, stream>>>(H0, fc0w, fc0b, fc1w, fc1b, fc2w, fc2b,
                                    gstep, adjW, a_in, dadjW, tailp);
  };

  // step 1: branch(xe) -> x1 ; d = xo*tanh(x1) -> outo
  k_branch<<<bgrid, 320, 0, stream>>>(x, 0, wc5[0], wo5[0], b5[0], wc3[0], b3[0], H1, h7fA, Spart);
  graph_pipe(STa, gW, nullptr);
  k_hA<<<agrid, 256, 0, stream>>>(H1, h7fA, dadjW, HA, hA7f);
  k_mix<<<mgrid, 256, 0, stream>>>(H1, HA, h7fA, hA7f, dcw, dcb, x, oute, outo, 1);

  // step 2: branch(xo) -> x2 ; c = xe*tanh(x2) -> oute
  k_branch<<<bgrid, 320, 0, stream>>>(x, 1, wc5[1], wo5[1], b5[1], wc3[1], b3[1], H1, h7fA, Spart);
  graph_pipe(STa, gW + GN, nullptr);
  k_hA<<<agrid, 256, 0, stream>>>(H1, h7fA, dadjW, HA, hA7f);
  k_mix<<<mgrid, 256, 0, stream>>>(H1, HA, h7fA, hA7f, dcw, dcb, x, oute, outo, 2);

  // steps 3 & 4: run both branches BEFORE either epilogue overwrites d_out
  k_branch<<<bgrid, 320, 0, stream>>>(oute, -1, wc5[2], wo5[2], b5[2], wc3[2], b3[2], H1, h7fA, Spart);
  k_sredT<<<43, 256, 0, stream>>>(Spart, STa);
  k_branch<<<bgrid, 320, 0, stream>>>(outo, -1, wc5[3], wo5[3], b5[3], wc3[3], b3[3], H2, h7fB, Spart);
  k_sredT<<<43, 256, 0, stream>>>(Spart, STb);

  // step 3 rest: outo = d - x3
  k_s1h0<<<NNODE, 64, 0, stream>>>(STa, adjW, ggw, ggb, H0);
  k_fc<<<NNODE, 256, 0, stream>>>(H0, fc0w, fc0b, fc1w, fc1b, fc2w, fc2b,
                                  gW + 2*GN, adjW, a_in, dadjW, nullptr);
  k_hA<<<agrid, 256, 0, stream>>>(H1, h7fA, dadjW, HA, hA7f);
  k_mix<<<mgrid, 256, 0, stream>>>(H1, HA, h7fA, hA7f, dcw, dcb, x, oute, outo, 3);

  // step 4 rest: oute = c + x4 ; dadj -> tail
  k_s1h0<<<NNODE, 64, 0, stream>>>(STb, adjW, ggw, ggb, H0);
  k_fc<<<NNODE, 256, 0, stream>>>(H0, fc0w, fc0b, fc1w, fc1b, fc2w, fc2b,
                                  gW + 3*GN, adjW, a_in, dadjW, tail);
  k_hA<<<agrid, 256, 0, stream>>>(H2, h7fB, dadjW, HA, hA7f);
  k_mix<<<mgrid, 256, 0, stream>>>(H2, HA, h7fB, hA7f, dcw, dcb, x, oute, outo, 4);

  (void)in_sizes; (void)n_in; (void)out_size;
}

// Round 5
// 3263.610 us; speedup vs baseline: 4.9347x; 1.2427x over previous
//
#include <hip/hip_runtime.h>
#include <hip/hip_bf16.h>
#include <cstdint>
#include <cstddef>

using bf16 = __hip_bfloat16;

static constexpr int BBATCH = 8, CCH = 64, NNODE = 170, TT = 256;
static constexpr size_t HSZ  = (size_t)BBATCH * CCH * NNODE * TT;  // 22282240
static constexpr size_t H7SZ = (size_t)CCH * NNODE * TT;           // 2785280
static constexpr int GN = NNODE * NNODE;                           // 28900

__device__ __forceinline__ float b2f(bf16 v) { return __bfloat162float(v); }
__device__ __forceinline__ bf16  f2b(float v) { return __float2bfloat16(v); }

union BfU { bf16 h; unsigned short s; };
__device__ __forceinline__ unsigned pack2(float a, float b) {
  BfU x, y; x.h = f2b(a); y.h = f2b(b);
  return ((unsigned)y.s << 16) | x.s;
}

// ---------------- threefry2x32 (JAX-compatible, partitionable) ----------------
__device__ __forceinline__ unsigned rotl32(unsigned v, int d) { return (v << d) | (v >> (32 - d)); }

__device__ void threefry2x32(unsigned k0, unsigned k1, unsigned x0, unsigned x1,
                             unsigned& y0, unsigned& y1) {
  unsigned ks0 = k0, ks1 = k1, ks2 = k0 ^ k1 ^ 0x1BD11BDAu;
  x0 += ks0; x1 += ks1;
  const int ra[4] = {13, 15, 26, 6};
  const int rb[4] = {17, 29, 16, 24};
#pragma unroll
  for (int r = 0; r < 4; r++) { x0 += x1; x1 = rotl32(x1, ra[r]); x1 ^= x0; }
  x0 += ks1; x1 += ks2 + 1u;
#pragma unroll
  for (int r = 0; r < 4; r++) { x0 += x1; x1 = rotl32(x1, rb[r]); x1 ^= x0; }
  x0 += ks2; x1 += ks0 + 2u;
#pragma unroll
  for (int r = 0; r < 4; r++) { x0 += x1; x1 = rotl32(x1, ra[r]); x1 ^= x0; }
  x0 += ks0; x1 += ks1 + 3u;
#pragma unroll
  for (int r = 0; r < 4; r++) { x0 += x1; x1 = rotl32(x1, rb[r]); x1 ^= x0; }
  x0 += ks1; x1 += ks2 + 4u;
#pragma unroll
  for (int r = 0; r < 4; r++) { x0 += x1; x1 = rotl32(x1, ra[r]); x1 ^= x0; }
  x0 += ks2; x1 += ks0 + 5u;
  y0 = x0; y1 = x1;
}

__global__ void k_keys(unsigned* keys) {
  int j = threadIdx.x;
  if (j < 4) {
    unsigned y0, y1;
    threefry2x32(0u, 42u, 0u, (unsigned)j, y0, y1);
    keys[2*j] = y0; keys[2*j+1] = y1;
  }
}

__global__ __launch_bounds__(256) void k_gumbel(const unsigned* __restrict__ keys,
                                                float* __restrict__ g) {
  int idx = blockIdx.x * 256 + threadIdx.x;
  if (idx >= 4 * GN) return;
  int w = idx / GN, i = idx % GN;
  unsigned y0, y1;
  threefry2x32(keys[2*w], keys[2*w+1], 0u, (unsigned)i, y0, y1);
  unsigned bits = y0 ^ y1;
  unsigned fb = (bits >> 9) | 0x3f800000u;
  float u = __uint_as_float(fb) - 1.0f;
  g[idx] = -logf(-logf(u + 1e-20f) + 1e-20f);
}

// ---------------- adj = softmax(relu(nv1@nv2), axis=1) ----------------
__global__ __launch_bounds__(256) void k_adj(const float* __restrict__ nv1,
                                             const float* __restrict__ nv2,
                                             float* __restrict__ adj) {
  int i = blockIdx.x, j = threadIdx.x;
  __shared__ float red[256];
  float val = 0.f, r = -1e30f;
  if (j < NNODE) {
    float acc = 0.f;
    for (int k = 0; k < 10; k++) acc += nv1[i*10+k] * nv2[k*NNODE+j];
    val = acc > 0.f ? acc : 0.f;
    r = val;
  }
  red[j] = r; __syncthreads();
  for (int s = 128; s; s >>= 1) { if (j < s) red[j] = fmaxf(red[j], red[j+s]); __syncthreads(); }
  float m = red[0]; __syncthreads();
  float e = (j < NNODE) ? expf(val - m) : 0.f;
  red[j] = e; __syncthreads();
  for (int s = 128; s; s >>= 1) { if (j < s) red[j] += red[j+s]; __syncthreads(); }
  if (j < NNODE) adj[i*NNODE+j] = e / red[0];
}

// ---------------- weight repacks: transpose to [c][k][o] for lane-coalesced loads ----
__global__ __launch_bounds__(256) void k_rep5T(const float* __restrict__ w, float* __restrict__ out) {
  int idx = blockIdx.x * 256 + threadIdx.x;
  if (idx >= 64*64*5) return;
  int oc = idx / 5, k = idx - oc * 5;
  int o = oc >> 6, c = oc & 63;
  out[(c*5 + k)*64 + o] = w[idx];
}
__global__ __launch_bounds__(256) void k_rep3T(const float* __restrict__ w, float* __restrict__ out) {
  int idx = blockIdx.x * 256 + threadIdx.x;
  if (idx >= 64*64*3) return;
  int oc = idx / 3, k = idx - oc * 3;
  int o = oc >> 6, c = oc & 63;
  out[(c*3 + k)*64 + o] = w[idx];
}

// ---------------- fused branch: conv5(edgepad)+leaky + conv3 + tanh ----------------
// grid (170, 4, 8), block 256 = 4 waves. lane = o (output channel),
// wave = 16-t subgroup. Weights: lane-coalesced loads from wT5/wT3 [c][k][o].
// x / h1 windows: wave-uniform float4 broadcasts from LDS.
__global__ __launch_bounds__(256) void k_branch(
    const float* __restrict__ src, int par,
    const float* __restrict__ wT5, const float* __restrict__ b5,
    const float* __restrict__ wT3, const float* __restrict__ b3,
    bf16* __restrict__ hout, float* __restrict__ h7f, float* __restrict__ Spart) {
  const int n = blockIdx.x, q = blockIdx.y, b = blockIdx.z;
  const int tid = threadIdx.x;
  const int o = tid & 63;
  const int w = __builtin_amdgcn_readfirstlane(tid >> 6);
  __shared__ float xs[64][72];     // x cols 0..69 (rows 288B, 16B-aligned); reused as out tile
  __shared__ float h1s[64][68];    // h1 cols 0..65 (rows 272B, 16B-aligned)
  const int t0 = q * 64;
  const int base = w * 16;
  const bool w3x = (w == 3);

  for (int i = tid; i < 64 * 70; i += 256) {
    int c = i / 70, pl = i - c * 70;
    int t = t0 + pl - 3; t = t < 0 ? 0 : (t > 255 ? 255 : t);
    size_t sb = ((size_t)b * 64 + c) * NNODE + n;
    xs[c][pl] = (par >= 0) ? src[sb * 512 + 2 * t + par] : src[sb * 256 + t];
  }
  __syncthreads();

  // ---- conv5 + leaky: acc[tt] = h1[o][base+tt]; wave 3 also halo cols 64,65
  {
    float acc[16];
#pragma unroll
    for (int tt = 0; tt < 16; tt++) acc[tt] = 0.f;
    float aH0 = 0.f, aH1 = 0.f;
    const float* wp = wT5 + o;
    for (int c = 0; c < 64; c++) {
      float xv[22];
      float4 v0 = *(const float4*)&xs[c][base + 0];
      float4 v1 = *(const float4*)&xs[c][base + 4];
      float4 v2 = *(const float4*)&xs[c][base + 8];
      float4 v3 = *(const float4*)&xs[c][base + 12];
      float4 v4 = *(const float4*)&xs[c][base + 16];
      xv[0]=v0.x; xv[1]=v0.y; xv[2]=v0.z; xv[3]=v0.w;
      xv[4]=v1.x; xv[5]=v1.y; xv[6]=v1.z; xv[7]=v1.w;
      xv[8]=v2.x; xv[9]=v2.y; xv[10]=v2.z; xv[11]=v2.w;
      xv[12]=v3.x; xv[13]=v3.y; xv[14]=v3.z; xv[15]=v3.w;
      xv[16]=v4.x; xv[17]=v4.y; xv[18]=v4.z; xv[19]=v4.w;
      if (w3x) { float2 vt = *(const float2*)&xs[c][68]; xv[20]=vt.x; xv[21]=vt.y; }
      float w0 = wp[0], w1 = wp[64], w2 = wp[128], w3 = wp[192], w4 = wp[256];
      wp += 320;
#pragma unroll
      for (int tt = 0; tt < 16; tt++)
        acc[tt] += w0*xv[tt] + w1*xv[tt+1] + w2*xv[tt+2] + w3*xv[tt+3] + w4*xv[tt+4];
      if (w3x) {
        aH0 += w0*xv[16] + w1*xv[17] + w2*xv[18] + w3*xv[19] + w4*xv[20];
        aH1 += w0*xv[17] + w1*xv[18] + w2*xv[19] + w3*xv[20] + w4*xv[21];
      }
    }
    float bias = b5[o];
#pragma unroll
    for (int tt = 0; tt < 16; tt++) {
      float v = acc[tt] + bias;
      h1s[o][base + tt] = v >= 0.f ? v : 0.01f * v;
    }
    if (w3x) {
      float u0 = aH0 + bias, u1 = aH1 + bias;
      h1s[o][64] = u0 >= 0.f ? u0 : 0.01f * u0;
      h1s[o][65] = u1 >= 0.f ? u1 : 0.01f * u1;
    }
  }
  __syncthreads();

  // ---- conv3 + tanh -> xs[o][base+tt]
  {
    float acc[16];
#pragma unroll
    for (int tt = 0; tt < 16; tt++) acc[tt] = 0.f;
    const float* wp = wT3 + o;
    for (int c = 0; c < 64; c++) {
      float hv[18];
      float4 v0 = *(const float4*)&h1s[c][base + 0];
      float4 v1 = *(const float4*)&h1s[c][base + 4];
      float4 v2 = *(const float4*)&h1s[c][base + 8];
      float4 v3 = *(const float4*)&h1s[c][base + 12];
      float4 v4 = *(const float4*)&h1s[c][base + 16];
      hv[0]=v0.x; hv[1]=v0.y; hv[2]=v0.z; hv[3]=v0.w;
      hv[4]=v1.x; hv[5]=v1.y; hv[6]=v1.z; hv[7]=v1.w;
      hv[8]=v2.x; hv[9]=v2.y; hv[10]=v2.z; hv[11]=v2.w;
      hv[12]=v3.x; hv[13]=v3.y; hv[14]=v3.z; hv[15]=v3.w;
      hv[16]=v4.x; hv[17]=v4.y;
      float w0 = wp[0], w1 = wp[64], w2 = wp[128];
      wp += 192;
#pragma unroll
      for (int tt = 0; tt < 16; tt++)
        acc[tt] += w0*hv[tt] + w1*hv[tt+1] + w2*hv[tt+2];
    }
    float bias = b3[o];
#pragma unroll
    for (int tt = 0; tt < 16; tt++) acc[tt] = tanhf(acc[tt] + bias);
    __syncthreads();   // all h1s/xs readers done before overwrite
#pragma unroll
    for (int tt = 0; tt < 16; tt++) xs[o][base + tt] = acc[tt];
  }
  __syncthreads();

  // ---- coalesced store
  {
    const int ro = tid >> 2, rq = tid & 3;
    float4 v0 = *(const float4*)&xs[ro][rq*16 + 0];
    float4 v1 = *(const float4*)&xs[ro][rq*16 + 4];
    float4 v2 = *(const float4*)&xs[ro][rq*16 + 8];
    float4 v3 = *(const float4*)&xs[ro][rq*16 + 12];
    if (b == 7) {
      float* dst = h7f + ((size_t)ro * NNODE + n) * TT + t0 + rq*16;
      *(float4*)&dst[0] = v0; *(float4*)&dst[4] = v1;
      *(float4*)&dst[8] = v2; *(float4*)&dst[12] = v3;
      float s = v0.x+v0.y+v0.z+v0.w + v1.x+v1.y+v1.z+v1.w
              + v2.x+v2.y+v2.z+v2.w + v3.x+v3.y+v3.z+v3.w;
      s += __shfl_xor(s, 1, 4);
      s += __shfl_xor(s, 2, 4);
      if (rq == 0) Spart[(q * 64 + ro) * NNODE + n] = s;
    } else {
      bf16* dst = hout + (((size_t)b * 64 + ro) * NNODE + n) * TT + t0 + rq*16;
      uint4 p0, p1;
      p0.x = pack2(v0.x, v0.y); p0.y = pack2(v0.z, v0.w);
      p0.z = pack2(v1.x, v1.y); p0.w = pack2(v1.z, v1.w);
      p1.x = pack2(v2.x, v2.y); p1.y = pack2(v2.z, v2.w);
      p1.z = pack2(v3.x, v3.y); p1.w = pack2(v3.z, v3.w);
      *(uint4*)&dst[0] = p0;
      *(uint4*)&dst[8] = p1;
    }
  }
}

// ---------------- ST[n][c] = sum_q Spart ----------------
__global__ __launch_bounds__(256) void k_sredT(const float* __restrict__ Spart, float* __restrict__ ST) {
  int idx = blockIdx.x * 256 + threadIdx.x;
  if (idx >= CCH * NNODE) return;
  int nn = idx >> 6, c = idx & 63;
  float acc = 0.f;
#pragma unroll
  for (int qq = 0; qq < 4; qq++) acc += Spart[(qq * 64 + c) * NNODE + nn];
  ST[idx] = acc;
}

// ---------------- fused S1 + H0 (block per node n, 64 threads) ----------------
__global__ __launch_bounds__(64) void k_s1h0(const float* __restrict__ ST, const float* __restrict__ adj,
                                             const float* __restrict__ ggw, const float* __restrict__ ggb,
                                             float* __restrict__ H0) {
  const int n = blockIdx.x;
  const int tid = threadIdx.x;
  __shared__ float s1[64], sc[64];
  {
    const int c = tid;
    float acc = 0.f;
    for (int nn = 0; nn < NNODE; nn++) acc += ST[nn*64 + c] * adj[nn*NNODE + n];
    s1[c] = acc;
    sc[c] = ST[n*64 + c];
  }
  __syncthreads();
  {
    const int o = tid;
    float acc = 256.f * ggb[o];
    for (int c = 0; c < 64; c++)
      acc += ggw[o*128 + c] * sc[c] + ggw[o*128 + 64 + c] * s1[c];
    H0[n*64 + o] = acc;
  }
}

// ---------------- fused fc0+fc1+fc2 + gumbel-argmax + dadj (block per row i) ----------------
__global__ __launch_bounds__(256) void k_fc(const float* __restrict__ H0,
    const float* __restrict__ fc0w, const float* __restrict__ fc0b,
    const float* __restrict__ fc1w, const float* __restrict__ fc1b,
    const float* __restrict__ fc2w, const float* __restrict__ fc2b,
    const float* __restrict__ g, const float* __restrict__ adj,
    const float* __restrict__ a_in,
    float* __restrict__ dadj, float* __restrict__ out_tail) {
  const int i = blockIdx.x;
  const int tid = threadIdx.x;
  __shared__ float h0r[64];
  __shared__ float a1r[NNODE];
  __shared__ float a2r[340];
  __shared__ float vred[256];
  __shared__ int ired[256];
  if (tid < 64) h0r[tid] = H0[i*64 + tid];
  __syncthreads();
  if (tid < NNODE) {
    float acc = fc0b[tid];
    for (int o = 0; o < 64; o++) acc += h0r[o] * fc0w[tid*64 + o];
    a1r[tid] = tanhf(acc);
  }
  __syncthreads();
  for (int j = tid; j < 340; j += 256) {
    float acc = fc1b[j];
    for (int k = 0; k < NNODE; k++) acc += a1r[k] * fc1w[j*NNODE + k];
    a2r[j] = tanhf(acc);
  }
  __syncthreads();
  float v = -1e30f;
  if (tid < NNODE) {
    float acc = fc2b[tid];
    for (int k = 0; k < 340; k++) acc += a2r[k] * fc2w[tid*340 + k];
    v = tanhf(acc) + g[i*NNODE + tid];
  }
  vred[tid] = v; ired[tid] = tid;
  __syncthreads();
  for (int s = 128; s; s >>= 1) {
    if (tid < s) {
      if (vred[tid+s] > vred[tid]) { vred[tid] = vred[tid+s]; ired[tid] = ired[tid+s]; }
    }
    __syncthreads();
  }
  int jmax = ired[0];
  float a = a_in[0];
  if (tid < NNODE) {
    float la = (tid == jmax && jmax != i) ? 1.f : 0.f;
    float dv = la * a + adj[i*NNODE + tid] * (1.f - a);
    dadj[i*NNODE + tid] = dv;
    if (out_tail) out_tail[i*NNODE + tid] = dv;
  }
}

// ---------------- hA = einsum('bcnt,nm->bcmt', h, dadj) ----------------
__global__ __launch_bounds__(256) void k_hA(const bf16* __restrict__ h, const float* __restrict__ h7f,
                                            const float* __restrict__ dadj,
                                            bf16* __restrict__ hA, float* __restrict__ hA7f) {
  const int bc = blockIdx.x, tq = blockIdx.y;
  const int b = bc >> 6;
  const int t0 = tq * 32;
  const int tid = threadIdx.x;
  const int lane = tid & 63;
  const int w = __builtin_amdgcn_readfirstlane(tid >> 6);
  __shared__ float hs[170][33];
  if (b == 7) {
    const int c = bc & 63;
    for (int i = tid; i < 170*32; i += 256) {
      int nn = i >> 5, tl = i & 31;
      hs[nn][tl] = h7f[((size_t)c * NNODE + nn) * TT + t0 + tl];
    }
  } else {
    for (int i = tid; i < 170*32; i += 256) {
      int nn = i >> 5, tl = i & 31;
      hs[nn][tl] = b2f(h[((size_t)bc * NNODE + nn) * TT + t0 + tl]);
    }
  }
  __syncthreads();
  float acc0[8], acc1[8], acc2[8];
#pragma unroll
  for (int tt = 0; tt < 8; tt++) { acc0[tt] = 0.f; acc1[tt] = 0.f; acc2[tt] = 0.f; }
  const int toff = w * 8;
  for (int nn = 0; nn < NNODE; nn++) {
    float hv[8];
#pragma unroll
    for (int tt = 0; tt < 8; tt++) hv[tt] = hs[nn][toff + tt];
    const float* dr = &dadj[nn * NNODE];
    float w0 = dr[lane];
    float w1 = dr[64 + lane];
    float w2 = (lane < 42) ? dr[128 + lane] : 0.f;
#pragma unroll
    for (int tt = 0; tt < 8; tt++) {
      acc0[tt] += w0 * hv[tt];
      acc1[tt] += w1 * hv[tt];
      acc2[tt] += w2 * hv[tt];
    }
  }
  __syncthreads();
#pragma unroll
  for (int tt = 0; tt < 8; tt++) {
    hs[lane][toff + tt] = acc0[tt];
    hs[64 + lane][toff + tt] = acc1[tt];
    if (lane < 42) hs[128 + lane][toff + tt] = acc2[tt];
  }
  __syncthreads();
  if (tid < NNODE) {
    if (b == 7) {
      const int c = bc & 63;
      float* dst = hA7f + ((size_t)c * NNODE + tid) * TT + t0;
#pragma unroll
      for (int j = 0; j < 8; j++)
        *(float4*)&dst[j*4] = make_float4(hs[tid][j*4], hs[tid][j*4+1], hs[tid][j*4+2], hs[tid][j*4+3]);
    } else {
      bf16* dst = hA + ((size_t)bc * NNODE + tid) * TT + t0;
      unsigned u[16];
#pragma unroll
      for (int j = 0; j < 16; j++) u[j] = pack2(hs[tid][2*j], hs[tid][2*j+1]);
      *(uint4*)&dst[0]  = make_uint4(u[0],u[1],u[2],u[3]);
      *(uint4*)&dst[8]  = make_uint4(u[4],u[5],u[6],u[7]);
      *(uint4*)&dst[16] = make_uint4(u[8],u[9],u[10],u[11]);
      *(uint4*)&dst[24] = make_uint4(u[12],u[13],u[14],u[15]);
    }
  }
}

// ---------------- channel mix + residual + per-step epilogue (single pass) ----------------
__global__ __launch_bounds__(256) void k_mix(const bf16* __restrict__ h, const bf16* __restrict__ hA,
                                             const float* __restrict__ h7f, const float* __restrict__ hA7f,
                                             const float* __restrict__ dcw, const float* __restrict__ dcb,
                                             const float* __restrict__ x,
                                             float* __restrict__ oute, float* __restrict__ outo, int epi) {
  const int n = blockIdx.x, b = blockIdx.y;
  const int t = threadIdx.x;
  __shared__ float wT[128][64];   // wT[cf][o]
  for (int i = t; i < 8192; i += 256) {
    int o_ = i >> 7, cf_ = i & 127;
    wT[cf_][o_] = dcw[i];
  }
  __syncthreads();
  const bool b7 = (b == 7);
  float acc[64];
#pragma unroll
  for (int oo = 0; oo < 64; oo++) acc[oo] = 0.f;
  for (int cc = 0; cc < 64; cc++) {
    float hv, hav;
    if (b7) {
      size_t off = ((size_t)cc * NNODE + n) * TT + t;
      hv = h7f[off]; hav = hA7f[off];
    } else {
      size_t off = (((size_t)b * 64 + cc) * NNODE + n) * TT + t;
      hv = b2f(h[off]); hav = b2f(hA[off]);
    }
#pragma unroll
    for (int oo = 0; oo < 64; oo++)
      acc[oo] += wT[cc][oo] * hv + wT[64+cc][oo] * hav;
  }
#pragma unroll
  for (int oo = 0; oo < 64; oo++) {
    size_t oidx = (((size_t)b * 64 + oo) * NNODE + n) * TT + t;
    float hres = b7 ? h7f[((size_t)oo * NNODE + n) * TT + t] : b2f(h[oidx]);
    float v = acc[oo] + hres + dcb[oo];
    if (epi == 1) {
      outo[oidx] = x[(((size_t)b*64 + oo) * NNODE + n) * 512 + 2*t + 1] * tanhf(v);
    } else if (epi == 2) {
      oute[oidx] = x[(((size_t)b*64 + oo) * NNODE + n) * 512 + 2*t] * tanhf(v);
    } else if (epi == 3) {
      outo[oidx] -= v;
    } else {
      oute[oidx] += v;
    }
  }
}

// ---------------- host ----------------
extern "C" void kernel_launch(void* const* d_in, const int* in_sizes, int n_in,
                              void* d_out, int out_size, void* d_ws, size_t ws_size,
                              hipStream_t stream) {
  const float* x    = (const float*)d_in[0];
  const float* nv1  = (const float*)d_in[1];
  const float* nv2  = (const float*)d_in[2];
  const float* a_in = (const float*)d_in[3];
  const float *w5[4], *b5[4], *w3[4], *b3[4];
  for (int s = 0; s < 4; s++) {
    w5[s] = (const float*)d_in[4 + 4*s];
    b5[s] = (const float*)d_in[5 + 4*s];
    w3[s] = (const float*)d_in[6 + 4*s];
    b3[s] = (const float*)d_in[7 + 4*s];
  }
  const float* ggw  = (const float*)d_in[20];
  const float* ggb  = (const float*)d_in[21];
  const float* fc0w = (const float*)d_in[22];
  const float* fc0b = (const float*)d_in[23];
  const float* fc1w = (const float*)d_in[24];
  const float* fc1b = (const float*)d_in[25];
  const float* fc2w = (const float*)d_in[26];
  const float* fc2b = (const float*)d_in[27];
  const float* dcw  = (const float*)d_in[28];
  const float* dcb  = (const float*)d_in[29];

  char* p = (char*)d_ws;
  size_t used = 0;
  auto alloc = [&](size_t bytes) -> char* {
    char* r = p + used;
    used += (bytes + 255) & ~(size_t)255;
    return r;
  };
  float* adjW   = (float*)alloc(GN*4);
  float* dadjW  = (float*)alloc(GN*4);
  float* gW     = (float*)alloc(4*GN*4);
  unsigned* keys= (unsigned*)alloc(8*4);
  float* STa    = (float*)alloc(CCH*NNODE*4);
  float* STb    = (float*)alloc(CCH*NNODE*4);
  float* Spart  = (float*)alloc(4*CCH*NNODE*4);
  float* H0     = (float*)alloc(NNODE*CCH*4);
  float* wT5[4]; float* wT3[4];
  for (int s = 0; s < 4; s++) {
    wT5[s] = (float*)alloc(64*64*5*4);
    wT3[s] = (float*)alloc(64*64*3*4);
  }
  bf16* H1      = (bf16*)alloc(HSZ*2);
  bf16* H2      = (bf16*)alloc(HSZ*2);
  bf16* HA      = (bf16*)alloc(HSZ*2);
  float* h7fA   = (float*)alloc(H7SZ*4);
  float* h7fB   = (float*)alloc(H7SZ*4);
  float* hA7f   = (float*)alloc(H7SZ*4);
  if (used > ws_size) return;  // signature: output stays zero

  float* oute = (float*)d_out;
  float* outo = oute + HSZ;
  float* tail = oute + 2*HSZ;

  dim3 bgrid(NNODE, 4, BBATCH);
  dim3 agrid(512, 8);
  dim3 mgrid(NNODE, BBATCH);

  for (int s = 0; s < 4; s++) {
    k_rep5T<<<80, 256, 0, stream>>>(w5[s], wT5[s]);
    k_rep3T<<<48, 256, 0, stream>>>(w3[s], wT3[s]);
  }
  k_adj<<<NNODE, 256, 0, stream>>>(nv1, nv2, adjW);
  k_keys<<<1, 64, 0, stream>>>(keys);
  k_gumbel<<<(4*GN + 255)/256, 256, 0, stream>>>(keys, gW);

  auto graph_pipe = [&](float* ST, const float* gstep, float* tailp) {
    k_sredT<<<43, 256, 0, stream>>>(Spart, ST);
    k_s1h0<<<NNODE, 64, 0, stream>>>(ST, adjW, ggw, ggb, H0);
    k_fc<<<NNODE, 256, 0, stream>>>(H0, fc0w, fc0b, fc1w, fc1b, fc2w, fc2b,
                                    gstep, adjW, a_in, dadjW, tailp);
  };

  // step 1: branch(xe) -> x1 ; d = xo*tanh(x1) -> outo
  k_branch<<<bgrid, 256, 0, stream>>>(x, 0, wT5[0], b5[0], wT3[0], b3[0], H1, h7fA, Spart);
  graph_pipe(STa, gW, nullptr);
  k_hA<<<agrid, 256, 0, stream>>>(H1, h7fA, dadjW, HA, hA7f);
  k_mix<<<mgrid, 256, 0, stream>>>(H1, HA, h7fA, hA7f, dcw, dcb, x, oute, outo, 1);

  // step 2: branch(xo) -> x2 ; c = xe*tanh(x2) -> oute
  k_branch<<<bgrid, 256, 0, stream>>>(x, 1, wT5[1], b5[1], wT3[1], b3[1], H1, h7fA, Spart);
  graph_pipe(STa, gW + GN, nullptr);
  k_hA<<<agrid, 256, 0, stream>>>(H1, h7fA, dadjW, HA, hA7f);
  k_mix<<<mgrid, 256, 0, stream>>>(H1, HA, h7fA, hA7f, dcw, dcb, x, oute, outo, 2);

  // steps 3 & 4: run both branches BEFORE either epilogue overwrites d_out
  k_branch<<<bgrid, 256, 0, stream>>>(oute, -1, wT5[2], b5[2], wT3[2], b3[2], H1, h7fA, Spart);
  k_sredT<<<43, 256, 0, stream>>>(Spart, STa);
  k_branch<<<bgrid, 256, 0, stream>>>(outo, -1, wT5[3], b5[3], wT3[3], b3[3], H2, h7fB, Spart);
  k_sredT<<<43, 256, 0, stream>>>(Spart, STb);

  // step 3 rest: outo = d - x3
  k_s1h0<<<NNODE, 64, 0, stream>>>(STa, adjW, ggw, ggb, H0);
  k_fc<<<NNODE, 256, 0, stream>>>(H0, fc0w, fc0b, fc1w, fc1b, fc2w, fc2b,
                                  gW + 2*GN, adjW, a_in, dadjW, nullptr);
  k_hA<<<agrid, 256, 0, stream>>>(H1, h7fA, dadjW, HA, hA7f);
  k_mix<<<mgrid, 256, 0, stream>>>(H1, HA, h7fA, hA7f, dcw, dcb, x, oute, outo, 3);

  // step 4 rest: oute = c + x4 ; dadj -> tail
  k_s1h0<<<NNODE, 64, 0, stream>>>(STb, adjW, ggw, ggb, H0);
  k_fc<<<NNODE, 256, 0, stream>>>(H0, fc0w, fc0b, fc1w, fc1b, fc2w, fc2b,
                                  gW + 3*GN, adjW, a_in, dadjW, tail);
  k_hA<<<agrid, 256, 0, stream>>>(H2, h7fB, dadjW, HA, hA7f);
  k_mix<<<mgrid, 256, 0, stream>>>(H2, HA, h7fB, hA7f, dcw, dcb, x, oute, outo, 4);

  (void)in_sizes; (void)n_in; (void)out_size;
}

// Round 6
// 2222.995 us; speedup vs baseline: 7.2447x; 1.4681x over previous
//
#include <hip/hip_runtime.h>
#include <hip/hip_bf16.h>
#include <cstdint>
#include <cstddef>

using bf16 = __hip_bfloat16;

static constexpr int BBATCH = 8, CCH = 64, NNODE = 170, TT = 256;
static constexpr size_t HSZ  = (size_t)BBATCH * CCH * NNODE * TT;  // 22282240
static constexpr size_t H7SZ = (size_t)CCH * NNODE * TT;           // 2785280
static constexpr int GN = NNODE * NNODE;                           // 28900

typedef __attribute__((ext_vector_type(8))) short short8v;
typedef __attribute__((ext_vector_type(4))) float f32x4;

__device__ __forceinline__ float b2f(bf16 v) { return __bfloat162float(v); }
__device__ __forceinline__ bf16  f2b(float v) { return __float2bfloat16(v); }

union BfU { bf16 h; unsigned short s; };
__device__ __forceinline__ unsigned short bfbits(float v) { BfU u; u.h = f2b(v); return u.s; }
__device__ __forceinline__ unsigned pack2(float a, float b) {
  return ((unsigned)bfbits(b) << 16) | bfbits(a);
}

// ---------------- threefry2x32 (JAX-compatible, partitionable) ----------------
__device__ __forceinline__ unsigned rotl32(unsigned v, int d) { return (v << d) | (v >> (32 - d)); }

__device__ void threefry2x32(unsigned k0, unsigned k1, unsigned x0, unsigned x1,
                             unsigned& y0, unsigned& y1) {
  unsigned ks0 = k0, ks1 = k1, ks2 = k0 ^ k1 ^ 0x1BD11BDAu;
  x0 += ks0; x1 += ks1;
  const int ra[4] = {13, 15, 26, 6};
  const int rb[4] = {17, 29, 16, 24};
#pragma unroll
  for (int r = 0; r < 4; r++) { x0 += x1; x1 = rotl32(x1, ra[r]); x1 ^= x0; }
  x0 += ks1; x1 += ks2 + 1u;
#pragma unroll
  for (int r = 0; r < 4; r++) { x0 += x1; x1 = rotl32(x1, rb[r]); x1 ^= x0; }
  x0 += ks2; x1 += ks0 + 2u;
#pragma unroll
  for (int r = 0; r < 4; r++) { x0 += x1; x1 = rotl32(x1, ra[r]); x1 ^= x0; }
  x0 += ks0; x1 += ks1 + 3u;
#pragma unroll
  for (int r = 0; r < 4; r++) { x0 += x1; x1 = rotl32(x1, rb[r]); x1 ^= x0; }
  x0 += ks1; x1 += ks2 + 4u;
#pragma unroll
  for (int r = 0; r < 4; r++) { x0 += x1; x1 = rotl32(x1, ra[r]); x1 ^= x0; }
  x0 += ks2; x1 += ks0 + 5u;
  y0 = x0; y1 = x1;
}

__global__ void k_keys(unsigned* keys) {
  int j = threadIdx.x;
  if (j < 4) {
    unsigned y0, y1;
    threefry2x32(0u, 42u, 0u, (unsigned)j, y0, y1);
    keys[2*j] = y0; keys[2*j+1] = y1;
  }
}

__global__ __launch_bounds__(256) void k_gumbel(const unsigned* __restrict__ keys,
                                                float* __restrict__ g) {
  int idx = blockIdx.x * 256 + threadIdx.x;
  if (idx >= 4 * GN) return;
  int w = idx / GN, i = idx % GN;
  unsigned y0, y1;
  threefry2x32(keys[2*w], keys[2*w+1], 0u, (unsigned)i, y0, y1);
  unsigned bits = y0 ^ y1;
  unsigned fb = (bits >> 9) | 0x3f800000u;
  float u = __uint_as_float(fb) - 1.0f;
  g[idx] = -logf(-logf(u + 1e-20f) + 1e-20f);
}

// ---------------- adj = softmax(relu(nv1@nv2), axis=1) ----------------
__global__ __launch_bounds__(256) void k_adj(const float* __restrict__ nv1,
                                             const float* __restrict__ nv2,
                                             float* __restrict__ adj) {
  int i = blockIdx.x, j = threadIdx.x;
  __shared__ float red[256];
  float val = 0.f, r = -1e30f;
  if (j < NNODE) {
    float acc = 0.f;
    for (int k = 0; k < 10; k++) acc += nv1[i*10+k] * nv2[k*NNODE+j];
    val = acc > 0.f ? acc : 0.f;
    r = val;
  }
  red[j] = r; __syncthreads();
  for (int s = 128; s; s >>= 1) { if (j < s) red[j] = fmaxf(red[j], red[j+s]); __syncthreads(); }
  float m = red[0]; __syncthreads();
  float e = (j < NNODE) ? expf(val - m) : 0.f;
  red[j] = e; __syncthreads();
  for (int s = 128; s; s >>= 1) { if (j < s) red[j] += red[j+s]; __syncthreads(); }
  if (j < NNODE) adj[i*NNODE+j] = e / red[0];
}

// ---------------- weight repacks ----------------
// fp32 path: w5 (o,c,5) -> wT5 (c,k,o); w3 -> wT3 (c,k,o)
__global__ __launch_bounds__(256) void k_rep5T(const float* __restrict__ w, float* __restrict__ out) {
  int idx = blockIdx.x * 256 + threadIdx.x;
  if (idx >= 64*64*5) return;
  int oc = idx / 5, k = idx - oc * 5;
  int o = oc >> 6, c = oc & 63;
  out[(c*5 + k)*64 + o] = w[idx];
}
__global__ __launch_bounds__(256) void k_rep3T(const float* __restrict__ w, float* __restrict__ out) {
  int idx = blockIdx.x * 256 + threadIdx.x;
  if (idx >= 64*64*3) return;
  int oc = idx / 3, k = idx - oc * 3;
  int o = oc >> 6, c = oc & 63;
  out[(c*3 + k)*64 + o] = w[idx];
}
// mfma path: A-fragment pack. out[(((k*2+ks)*4+mi)*64+l)*8+j] = bf16(w[o=mi*16+(l&15)][c=ks*32+(l>>4)*8+j][k])
__global__ __launch_bounds__(256) void k_pack5(const float* __restrict__ w, short* __restrict__ out) {
  int idx = blockIdx.x * 256 + threadIdx.x;
  if (idx >= 20480) return;
  int j = idx & 7, l = (idx >> 3) & 63, mi = (idx >> 9) & 3, ks = (idx >> 11) & 1, k = idx >> 12;
  int o = mi*16 + (l & 15);
  int c = ks*32 + (l >> 4)*8 + j;
  out[idx] = (short)bfbits(w[(o*64 + c)*5 + k]);
}
__global__ __launch_bounds__(256) void k_pack3(const float* __restrict__ w, short* __restrict__ out) {
  int idx = blockIdx.x * 256 + threadIdx.x;
  if (idx >= 12288) return;
  int j = idx & 7, l = (idx >> 3) & 63, mi = (idx >> 9) & 3, ks = (idx >> 11) & 1, k = idx >> 12;
  int o = mi*16 + (l & 15);
  int c = ks*32 + (l >> 4)*8 + j;
  out[idx] = (short)bfbits(w[(o*64 + c)*3 + k]);
}

// ---------------- fused branch: conv5(edgepad)+leaky + conv3 + tanh ----------------
// grid (170, 4, 8), block 256. b<7: bf16 MFMA implicit-GEMM path. b==7: exact fp32 VALU path.
__global__ __launch_bounds__(256) void k_branch(
    const float* __restrict__ src, int par,
    const float* __restrict__ wT5, const float* __restrict__ b5,
    const float* __restrict__ wT3, const float* __restrict__ b3,
    const short* __restrict__ wp5, const short* __restrict__ wp3,
    bf16* __restrict__ hout, float* __restrict__ h7f, float* __restrict__ Spart) {
  const int n = blockIdx.x, q = blockIdx.y, b = blockIdx.z;
  const int tid = threadIdx.x;
  const int l = tid & 63;
  const int w = __builtin_amdgcn_readfirstlane(tid >> 6);
  const int t0 = q * 64;
  __shared__ char lds[35840];

  if (b == 7) {
    // ================= fp32 exact path (argmax chain) =================
    float (*xs)[72]  = (float(*)[72])lds;              // 18432 B
    float (*h1s)[68] = (float(*)[68])(lds + 18432);    // 17408 B
    const int o = l;
    const int base = w * 16;
    const bool w3x = (w == 3);

    for (int i = tid; i < 64 * 70; i += 256) {
      int c = i / 70, pl = i - c * 70;
      int t = t0 + pl - 3; t = t < 0 ? 0 : (t > 255 ? 255 : t);
      size_t sb = ((size_t)7 * 64 + c) * NNODE + n;
      xs[c][pl] = (par >= 0) ? src[sb * 512 + 2 * t + par] : src[sb * 256 + t];
    }
    __syncthreads();

    {
      float acc[16];
#pragma unroll
      for (int tt = 0; tt < 16; tt++) acc[tt] = 0.f;
      float aH0 = 0.f, aH1 = 0.f;
      const float* wp = wT5 + o;
      for (int c = 0; c < 64; c++) {
        float xv[22];
        float4 v0 = *(const float4*)&xs[c][base + 0];
        float4 v1 = *(const float4*)&xs[c][base + 4];
        float4 v2 = *(const float4*)&xs[c][base + 8];
        float4 v3 = *(const float4*)&xs[c][base + 12];
        float4 v4 = *(const float4*)&xs[c][base + 16];
        xv[0]=v0.x; xv[1]=v0.y; xv[2]=v0.z; xv[3]=v0.w;
        xv[4]=v1.x; xv[5]=v1.y; xv[6]=v1.z; xv[7]=v1.w;
        xv[8]=v2.x; xv[9]=v2.y; xv[10]=v2.z; xv[11]=v2.w;
        xv[12]=v3.x; xv[13]=v3.y; xv[14]=v3.z; xv[15]=v3.w;
        xv[16]=v4.x; xv[17]=v4.y; xv[18]=v4.z; xv[19]=v4.w;
        if (w3x) { float2 vt = *(const float2*)&xs[c][68]; xv[20]=vt.x; xv[21]=vt.y; }
        float w0 = wp[0], w1 = wp[64], w2 = wp[128], w3_ = wp[192], w4 = wp[256];
        wp += 320;
#pragma unroll
        for (int tt = 0; tt < 16; tt++)
          acc[tt] += w0*xv[tt] + w1*xv[tt+1] + w2*xv[tt+2] + w3_*xv[tt+3] + w4*xv[tt+4];
        if (w3x) {
          aH0 += w0*xv[16] + w1*xv[17] + w2*xv[18] + w3_*xv[19] + w4*xv[20];
          aH1 += w0*xv[17] + w1*xv[18] + w2*xv[19] + w3_*xv[20] + w4*xv[21];
        }
      }
      float bias = b5[o];
#pragma unroll
      for (int tt = 0; tt < 16; tt++) {
        float v = acc[tt] + bias;
        h1s[o][base + tt] = v >= 0.f ? v : 0.01f * v;
      }
      if (w3x) {
        float u0 = aH0 + bias, u1 = aH1 + bias;
        h1s[o][64] = u0 >= 0.f ? u0 : 0.01f * u0;
        h1s[o][65] = u1 >= 0.f ? u1 : 0.01f * u1;
      }
    }
    __syncthreads();

    {
      float acc[16];
#pragma unroll
      for (int tt = 0; tt < 16; tt++) acc[tt] = 0.f;
      const float* wp = wT3 + o;
      for (int c = 0; c < 64; c++) {
        float hv[18];
        float4 v0 = *(const float4*)&h1s[c][base + 0];
        float4 v1 = *(const float4*)&h1s[c][base + 4];
        float4 v2 = *(const float4*)&h1s[c][base + 8];
        float4 v3 = *(const float4*)&h1s[c][base + 12];
        float4 v4 = *(const float4*)&h1s[c][base + 16];
        hv[0]=v0.x; hv[1]=v0.y; hv[2]=v0.z; hv[3]=v0.w;
        hv[4]=v1.x; hv[5]=v1.y; hv[6]=v1.z; hv[7]=v1.w;
        hv[8]=v2.x; hv[9]=v2.y; hv[10]=v2.z; hv[11]=v2.w;
        hv[12]=v3.x; hv[13]=v3.y; hv[14]=v3.z; hv[15]=v3.w;
        hv[16]=v4.x; hv[17]=v4.y;
        float w0 = wp[0], w1 = wp[64], w2 = wp[128];
        wp += 192;
#pragma unroll
        for (int tt = 0; tt < 16; tt++)
          acc[tt] += w0*hv[tt] + w1*hv[tt+1] + w2*hv[tt+2];
      }
      float bias = b3[o];
#pragma unroll
      for (int tt = 0; tt < 16; tt++) acc[tt] = tanhf(acc[tt] + bias);
      __syncthreads();
#pragma unroll
      for (int tt = 0; tt < 16; tt++) xs[o][base + tt] = acc[tt];
    }
    __syncthreads();

    {
      const int ro = tid >> 2, rq = tid & 3;
      float4 v0 = *(const float4*)&xs[ro][rq*16 + 0];
      float4 v1 = *(const float4*)&xs[ro][rq*16 + 4];
      float4 v2 = *(const float4*)&xs[ro][rq*16 + 8];
      float4 v3 = *(const float4*)&xs[ro][rq*16 + 12];
      float* dst = h7f + ((size_t)ro * NNODE + n) * TT + t0 + rq*16;
      *(float4*)&dst[0] = v0; *(float4*)&dst[4] = v1;
      *(float4*)&dst[8] = v2; *(float4*)&dst[12] = v3;
      float s = v0.x+v0.y+v0.z+v0.w + v1.x+v1.y+v1.z+v1.w
              + v2.x+v2.y+v2.z+v2.w + v3.x+v3.y+v3.z+v3.w;
      s += __shfl_xor(s, 1, 4);
      s += __shfl_xor(s, 2, 4);
      if (rq == 0) Spart[(q * 64 + ro) * NNODE + n] = s;
    }
    return;
  }

  // ================= bf16 MFMA path (b < 7) =================
  // xs_T: rows t'=0..83 (84 rows x 128B, 16B-XOR swizzle), at lds+0
  // h1_T: rows t'=0..65 (66 rows x 128B), at lds+10752
  // out tile [o][t]: 64 rows x 144B, at lds+0 (reuses xs_T after conv5)
  const int mi = w;

  // stage x as bf16 transposed (rows 0..63: coalesced; rows 64..69: gather)
  for (int it = 0; it < 16; it++) {
    int c = it * 4 + w;
    int t = t0 + l - 3; t = t < 0 ? 0 : (t > 255 ? 255 : t);
    size_t sb = ((size_t)b * 64 + c) * NNODE + n;
    float v = (par >= 0) ? src[sb * 512 + 2 * t + par] : src[sb * 256 + t];
    *(short*)(lds + l*128 + ((2*c) ^ ((l & 7) << 4))) = (short)bfbits(v);
  }
  for (int i = tid; i < 6 * 64; i += 256) {
    int tr = 64 + (i >> 6);
    int c = i & 63;
    int t = t0 + tr - 3; if (t > 255) t = 255;
    size_t sb = ((size_t)b * 64 + c) * NNODE + n;
    float v = (par >= 0) ? src[sb * 512 + 2 * t + par] : src[sb * 256 + t];
    *(short*)(lds + tr*128 + ((2*c) ^ ((tr & 7) << 4))) = (short)bfbits(v);
  }
  __syncthreads();

  // conv5: 5 taps x 2 K-steps x (4 main + 1 halo) tiles
  f32x4 acc[5];
#pragma unroll
  for (int i = 0; i < 5; i++) acc[i] = (f32x4){0.f, 0.f, 0.f, 0.f};
  for (int k = 0; k < 5; k++) {
#pragma unroll
    for (int ks = 0; ks < 2; ks++) {
      short8v af = *(const short8v*)(wp5 + (size_t)((((k*2 + ks)*4 + mi)*64 + l) * 8));
      const int c0 = ks*32 + (l >> 4)*8;
#pragma unroll
      for (int ni = 0; ni < 5; ni++) {
        int tr = ni*16 + (l & 15) + k;
        short8v bf = *(const short8v*)(lds + tr*128 + ((2*c0) ^ ((tr & 7) << 4)));
        acc[ni] = __builtin_amdgcn_mfma_f32_16x16x32_bf16(af, bf, acc[ni], 0, 0, 0);
      }
    }
  }
  // bias + leaky -> h1_T (bf16, swizzled)
  {
    const int o0 = mi*16 + ((l >> 4) << 2);
    float4 bv = *(const float4*)&b5[o0];
    float bb[4] = {bv.x, bv.y, bv.z, bv.w};
#pragma unroll
    for (int ni = 0; ni < 4; ni++) {
      int tr = ni*16 + (l & 15);
      float v[4];
#pragma unroll
      for (int r = 0; r < 4; r++) {
        float u = acc[ni][r] + bb[r];
        v[r] = u >= 0.f ? u : 0.01f * u;
      }
      int colb = (2*o0) ^ ((tr & 7) << 4);
      *(uint2*)(lds + 10752 + tr*128 + colb) = make_uint2(pack2(v[0], v[1]), pack2(v[2], v[3]));
    }
    if ((l & 15) < 2) {
      int tr = 64 + (l & 15);
      float v[4];
#pragma unroll
      for (int r = 0; r < 4; r++) {
        float u = acc[4][r] + bb[r];
        v[r] = u >= 0.f ? u : 0.01f * u;
      }
      int colb = (2*o0) ^ ((tr & 7) << 4);
      *(uint2*)(lds + 10752 + tr*128 + colb) = make_uint2(pack2(v[0], v[1]), pack2(v[2], v[3]));
    }
  }
  __syncthreads();

  // conv3: 3 taps x 2 K-steps x 4 tiles
  f32x4 acc3[4];
#pragma unroll
  for (int i = 0; i < 4; i++) acc3[i] = (f32x4){0.f, 0.f, 0.f, 0.f};
  for (int k = 0; k < 3; k++) {
#pragma unroll
    for (int ks = 0; ks < 2; ks++) {
      short8v af = *(const short8v*)(wp3 + (size_t)((((k*2 + ks)*4 + mi)*64 + l) * 8));
      const int c0 = ks*32 + (l >> 4)*8;
#pragma unroll
      for (int ni = 0; ni < 4; ni++) {
        int tr = ni*16 + (l & 15) + k;
        short8v bf = *(const short8v*)(lds + 10752 + tr*128 + ((2*c0) ^ ((tr & 7) << 4)));
        acc3[ni] = __builtin_amdgcn_mfma_f32_16x16x32_bf16(af, bf, acc3[ni], 0, 0, 0);
      }
    }
  }
  // bias + tanh -> out tile [o][t] (stride 144B)
  {
    const int o0 = mi*16 + ((l >> 4) << 2);
    float4 bv = *(const float4*)&b3[o0];
    float bb[4] = {bv.x, bv.y, bv.z, bv.w};
#pragma unroll
    for (int ni = 0; ni < 4; ni++) {
      int t = ni*16 + (l & 15);
#pragma unroll
      for (int r = 0; r < 4; r++) {
        float v = tanhf(acc3[ni][r] + bb[r]);
        *(short*)(lds + (o0 + r)*144 + t*2) = (short)bfbits(v);
      }
    }
  }
  __syncthreads();

  // coalesced store
  {
    const int ro = tid >> 2, rq = tid & 3;
    uint4 p0 = *(const uint4*)(lds + ro*144 + rq*32);
    uint4 p1 = *(const uint4*)(lds + ro*144 + rq*32 + 16);
    bf16* dst = hout + (((size_t)b * 64 + ro) * NNODE + n) * TT + t0 + rq*16;
    *(uint4*)&dst[0] = p0;
    *(uint4*)&dst[8] = p1;
  }
}

// ---------------- ST[n][c] = sum_q Spart ----------------
__global__ __launch_bounds__(256) void k_sredT(const float* __restrict__ Spart, float* __restrict__ ST) {
  int idx = blockIdx.x * 256 + threadIdx.x;
  if (idx >= CCH * NNODE) return;
  int nn = idx >> 6, c = idx & 63;
  float acc = 0.f;
#pragma unroll
  for (int qq = 0; qq < 4; qq++) acc += Spart[(qq * 64 + c) * NNODE + nn];
  ST[idx] = acc;
}

// ---------------- fused S1 + H0 (block per node n, 64 threads) ----------------
__global__ __launch_bounds__(64) void k_s1h0(const float* __restrict__ ST, const float* __restrict__ adj,
                                             const float* __restrict__ ggw, const float* __restrict__ ggb,
                                             float* __restrict__ H0) {
  const int n = blockIdx.x;
  const int tid = threadIdx.x;
  __shared__ float s1[64], sc[64];
  {
    const int c = tid;
    float acc = 0.f;
    for (int nn = 0; nn < NNODE; nn++) acc += ST[nn*64 + c] * adj[nn*NNODE + n];
    s1[c] = acc;
    sc[c] = ST[n*64 + c];
  }
  __syncthreads();
  {
    const int o = tid;
    float acc = 256.f * ggb[o];
    for (int c = 0; c < 64; c++)
      acc += ggw[o*128 + c] * sc[c] + ggw[o*128 + 64 + c] * s1[c];
    H0[n*64 + o] = acc;
  }
}

// ---------------- fused fc0+fc1+fc2 + gumbel-argmax + dadj (block per row i) ----------------
__global__ __launch_bounds__(256) void k_fc(const float* __restrict__ H0,
    const float* __restrict__ fc0w, const float* __restrict__ fc0b,
    const float* __restrict__ fc1w, const float* __restrict__ fc1b,
    const float* __restrict__ fc2w, const float* __restrict__ fc2b,
    const float* __restrict__ g, const float* __restrict__ adj,
    const float* __restrict__ a_in,
    float* __restrict__ dadj, float* __restrict__ out_tail) {
  const int i = blockIdx.x;
  const int tid = threadIdx.x;
  __shared__ float h0r[64];
  __shared__ float a1r[NNODE];
  __shared__ float a2r[340];
  __shared__ float vred[256];
  __shared__ int ired[256];
  if (tid < 64) h0r[tid] = H0[i*64 + tid];
  __syncthreads();
  if (tid < NNODE) {
    float acc = fc0b[tid];
    for (int o = 0; o < 64; o++) acc += h0r[o] * fc0w[tid*64 + o];
    a1r[tid] = tanhf(acc);
  }
  __syncthreads();
  for (int j = tid; j < 340; j += 256) {
    float acc = fc1b[j];
    for (int k = 0; k < NNODE; k++) acc += a1r[k] * fc1w[j*NNODE + k];
    a2r[j] = tanhf(acc);
  }
  __syncthreads();
  float v = -1e30f;
  if (tid < NNODE) {
    float acc = fc2b[tid];
    for (int k = 0; k < 340; k++) acc += a2r[k] * fc2w[tid*340 + k];
    v = tanhf(acc) + g[i*NNODE + tid];
  }
  vred[tid] = v; ired[tid] = tid;
  __syncthreads();
  for (int s = 128; s; s >>= 1) {
    if (tid < s) {
      if (vred[tid+s] > vred[tid]) { vred[tid] = vred[tid+s]; ired[tid] = ired[tid+s]; }
    }
    __syncthreads();
  }
  int jmax = ired[0];
  float a = a_in[0];
  if (tid < NNODE) {
    float la = (tid == jmax && jmax != i) ? 1.f : 0.f;
    float dv = la * a + adj[i*NNODE + tid] * (1.f - a);
    dadj[i*NNODE + tid] = dv;
    if (out_tail) out_tail[i*NNODE + tid] = dv;
  }
}

// ---------------- hA = einsum('bcnt,nm->bcmt', h, dadj) ----------------
__global__ __launch_bounds__(256) void k_hA(const bf16* __restrict__ h, const float* __restrict__ h7f,
                                            const float* __restrict__ dadj,
                                            bf16* __restrict__ hA, float* __restrict__ hA7f) {
  const int bc = blockIdx.x, tq = blockIdx.y;
  const int b = bc >> 6;
  const int t0 = tq * 32;
  const int tid = threadIdx.x;
  const int lane = tid & 63;
  const int w = __builtin_amdgcn_readfirstlane(tid >> 6);
  __shared__ float hs[170][33];
  if (b == 7) {
    const int c = bc & 63;
    for (int i = tid; i < 170*32; i += 256) {
      int nn = i >> 5, tl = i & 31;
      hs[nn][tl] = h7f[((size_t)c * NNODE + nn) * TT + t0 + tl];
    }
  } else {
    for (int i = tid; i < 170*32; i += 256) {
      int nn = i >> 5, tl = i & 31;
      hs[nn][tl] = b2f(h[((size_t)bc * NNODE + nn) * TT + t0 + tl]);
    }
  }
  __syncthreads();
  float acc0[8], acc1[8], acc2[8];
#pragma unroll
  for (int tt = 0; tt < 8; tt++) { acc0[tt] = 0.f; acc1[tt] = 0.f; acc2[tt] = 0.f; }
  const int toff = w * 8;
  for (int nn = 0; nn < NNODE; nn++) {
    float hv[8];
#pragma unroll
    for (int tt = 0; tt < 8; tt++) hv[tt] = hs[nn][toff + tt];
    const float* dr = &dadj[nn * NNODE];
    float w0 = dr[lane];
    float w1 = dr[64 + lane];
    float w2 = (lane < 42) ? dr[128 + lane] : 0.f;
#pragma unroll
    for (int tt = 0; tt < 8; tt++) {
      acc0[tt] += w0 * hv[tt];
      acc1[tt] += w1 * hv[tt];
      acc2[tt] += w2 * hv[tt];
    }
  }
  __syncthreads();
#pragma unroll
  for (int tt = 0; tt < 8; tt++) {
    hs[lane][toff + tt] = acc0[tt];
    hs[64 + lane][toff + tt] = acc1[tt];
    if (lane < 42) hs[128 + lane][toff + tt] = acc2[tt];
  }
  __syncthreads();
  if (tid < NNODE) {
    if (b == 7) {
      const int c = bc & 63;
      float* dst = hA7f + ((size_t)c * NNODE + tid) * TT + t0;
#pragma unroll
      for (int j = 0; j < 8; j++)
        *(float4*)&dst[j*4] = make_float4(hs[tid][j*4], hs[tid][j*4+1], hs[tid][j*4+2], hs[tid][j*4+3]);
    } else {
      bf16* dst = hA + ((size_t)bc * NNODE + tid) * TT + t0;
      unsigned u[16];
#pragma unroll
      for (int j = 0; j < 16; j++) u[j] = pack2(hs[tid][2*j], hs[tid][2*j+1]);
      *(uint4*)&dst[0]  = make_uint4(u[0],u[1],u[2],u[3]);
      *(uint4*)&dst[8]  = make_uint4(u[4],u[5],u[6],u[7]);
      *(uint4*)&dst[16] = make_uint4(u[8],u[9],u[10],u[11]);
      *(uint4*)&dst[24] = make_uint4(u[12],u[13],u[14],u[15]);
    }
  }
}

// ---------------- channel mix + residual + per-step epilogue (single pass) ----------------
__global__ __launch_bounds__(256) void k_mix(const bf16* __restrict__ h, const bf16* __restrict__ hA,
                                             const float* __restrict__ h7f, const float* __restrict__ hA7f,
                                             const float* __restrict__ dcw, const float* __restrict__ dcb,
                                             const float* __restrict__ x,
                                             float* __restrict__ oute, float* __restrict__ outo, int epi) {
  const int n = blockIdx.x, b = blockIdx.y;
  const int t = threadIdx.x;
  __shared__ float wT[128][64];   // wT[cf][o]
  for (int i = t; i < 8192; i += 256) {
    int o_ = i >> 7, cf_ = i & 127;
    wT[cf_][o_] = dcw[i];
  }
  __syncthreads();
  const bool b7 = (b == 7);
  float acc[64];
#pragma unroll
  for (int oo = 0; oo < 64; oo++) acc[oo] = 0.f;
  for (int cc = 0; cc < 64; cc++) {
    float hv, hav;
    if (b7) {
      size_t off = ((size_t)cc * NNODE + n) * TT + t;
      hv = h7f[off]; hav = hA7f[off];
    } else {
      size_t off = (((size_t)b * 64 + cc) * NNODE + n) * TT + t;
      hv = b2f(h[off]); hav = b2f(hA[off]);
    }
#pragma unroll
    for (int oo = 0; oo < 64; oo++)
      acc[oo] += wT[cc][oo] * hv + wT[64+cc][oo] * hav;
  }
#pragma unroll
  for (int oo = 0; oo < 64; oo++) {
    size_t oidx = (((size_t)b * 64 + oo) * NNODE + n) * TT + t;
    float hres = b7 ? h7f[((size_t)oo * NNODE + n) * TT + t] : b2f(h[oidx]);
    float v = acc[oo] + hres + dcb[oo];
    if (epi == 1) {
      outo[oidx] = x[(((size_t)b*64 + oo) * NNODE + n) * 512 + 2*t + 1] * tanhf(v);
    } else if (epi == 2) {
      oute[oidx] = x[(((size_t)b*64 + oo) * NNODE + n) * 512 + 2*t] * tanhf(v);
    } else if (epi == 3) {
      outo[oidx] -= v;
    } else {
      oute[oidx] += v;
    }
  }
}

// ---------------- host ----------------
extern "C" void kernel_launch(void* const* d_in, const int* in_sizes, int n_in,
                              void* d_out, int out_size, void* d_ws, size_t ws_size,
                              hipStream_t stream) {
  const float* x    = (const float*)d_in[0];
  const float* nv1  = (const float*)d_in[1];
  const float* nv2  = (const float*)d_in[2];
  const float* a_in = (const float*)d_in[3];
  const float *w5[4], *b5[4], *w3[4], *b3[4];
  for (int s = 0; s < 4; s++) {
    w5[s] = (const float*)d_in[4 + 4*s];
    b5[s] = (const float*)d_in[5 + 4*s];
    w3[s] = (const float*)d_in[6 + 4*s];
    b3[s] = (const float*)d_in[7 + 4*s];
  }
  const float* ggw  = (const float*)d_in[20];
  const float* ggb  = (const float*)d_in[21];
  const float* fc0w = (const float*)d_in[22];
  const float* fc0b = (const float*)d_in[23];
  const float* fc1w = (const float*)d_in[24];
  const float* fc1b = (const float*)d_in[25];
  const float* fc2w = (const float*)d_in[26];
  const float* fc2b = (const float*)d_in[27];
  const float* dcw  = (const float*)d_in[28];
  const float* dcb  = (const float*)d_in[29];

  char* p = (char*)d_ws;
  size_t used = 0;
  auto alloc = [&](size_t bytes) -> char* {
    char* r = p + used;
    used += (bytes + 255) & ~(size_t)255;
    return r;
  };
  float* adjW   = (float*)alloc(GN*4);
  float* dadjW  = (float*)alloc(GN*4);
  float* gW     = (float*)alloc(4*GN*4);
  unsigned* keys= (unsigned*)alloc(8*4);
  float* STa    = (float*)alloc(CCH*NNODE*4);
  float* STb    = (float*)alloc(CCH*NNODE*4);
  float* Spart  = (float*)alloc(4*CCH*NNODE*4);
  float* H0     = (float*)alloc(NNODE*CCH*4);
  float* wT5[4]; float* wT3[4];
  short* wp5[4]; short* wp3[4];
  for (int s = 0; s < 4; s++) {
    wT5[s] = (float*)alloc(64*64*5*4);
    wT3[s] = (float*)alloc(64*64*3*4);
    wp5[s] = (short*)alloc(20480*2);
    wp3[s] = (short*)alloc(12288*2);
  }
  bf16* H1      = (bf16*)alloc(HSZ*2);
  bf16* H2      = (bf16*)alloc(HSZ*2);
  bf16* HA      = (bf16*)alloc(HSZ*2);
  float* h7fA   = (float*)alloc(H7SZ*4);
  float* h7fB   = (float*)alloc(H7SZ*4);
  float* hA7f   = (float*)alloc(H7SZ*4);
  if (used > ws_size) return;  // signature: output stays zero

  float* oute = (float*)d_out;
  float* outo = oute + HSZ;
  float* tail = oute + 2*HSZ;

  dim3 bgrid(NNODE, 4, BBATCH);
  dim3 agrid(512, 8);
  dim3 mgrid(NNODE, BBATCH);

  for (int s = 0; s < 4; s++) {
    k_rep5T<<<80, 256, 0, stream>>>(w5[s], wT5[s]);
    k_rep3T<<<48, 256, 0, stream>>>(w3[s], wT3[s]);
    k_pack5<<<80, 256, 0, stream>>>(w5[s], wp5[s]);
    k_pack3<<<48, 256, 0, stream>>>(w3[s], wp3[s]);
  }
  k_adj<<<NNODE, 256, 0, stream>>>(nv1, nv2, adjW);
  k_keys<<<1, 64, 0, stream>>>(keys);
  k_gumbel<<<(4*GN + 255)/256, 256, 0, stream>>>(keys, gW);

  auto graph_pipe = [&](float* ST, const float* gstep, float* tailp) {
    k_sredT<<<43, 256, 0, stream>>>(Spart, ST);
    k_s1h0<<<NNODE, 64, 0, stream>>>(ST, adjW, ggw, ggb, H0);
    k_fc<<<NNODE, 256, 0, stream>>>(H0, fc0w, fc0b, fc1w, fc1b, fc2w, fc2b,
                                    gstep, adjW, a_in, dadjW, tailp);
  };

  // step 1: branch(xe) -> x1 ; d = xo*tanh(x1) -> outo
  k_branch<<<bgrid, 256, 0, stream>>>(x, 0, wT5[0], b5[0], wT3[0], b3[0], wp5[0], wp3[0], H1, h7fA, Spart);
  graph_pipe(STa, gW, nullptr);
  k_hA<<<agrid, 256, 0, stream>>>(H1, h7fA, dadjW, HA, hA7f);
  k_mix<<<mgrid, 256, 0, stream>>>(H1, HA, h7fA, hA7f, dcw, dcb, x, oute, outo, 1);

  // step 2: branch(xo) -> x2 ; c = xe*tanh(x2) -> oute
  k_branch<<<bgrid, 256, 0, stream>>>(x, 1, wT5[1], b5[1], wT3[1], b3[1], wp5[1], wp3[1], H1, h7fA, Spart);
  graph_pipe(STa, gW + GN, nullptr);
  k_hA<<<agrid, 256, 0, stream>>>(H1, h7fA, dadjW, HA, hA7f);
  k_mix<<<mgrid, 256, 0, stream>>>(H1, HA, h7fA, hA7f, dcw, dcb, x, oute, outo, 2);

  // steps 3 & 4: run both branches BEFORE either epilogue overwrites d_out
  k_branch<<<bgrid, 256, 0, stream>>>(oute, -1, wT5[2], b5[2], wT3[2], b3[2], wp5[2], wp3[2], H1, h7fA, Spart);
  k_sredT<<<43, 256, 0, stream>>>(Spart, STa);
  k_branch<<<bgrid, 256, 0, stream>>>(outo, -1, wT5[3], b5[3], wT3[3], b3[3], wp5[3], wp3[3], H2, h7fB, Spart);
  k_sredT<<<43, 256, 0, stream>>>(Spart, STb);

  // step 3 rest: outo = d - x3
  k_s1h0<<<NNODE, 64, 0, stream>>>(STa, adjW, ggw, ggb, H0);
  k_fc<<<NNODE, 256, 0, stream>>>(H0, fc0w, fc0b, fc1w, fc1b, fc2w, fc2b,
                                  gW + 2*GN, adjW, a_in, dadjW, nullptr);
  k_hA<<<agrid, 256, 0, stream>>>(H1, h7fA, dadjW, HA, hA7f);
  k_mix<<<mgrid, 256, 0, stream>>>(H1, HA, h7fA, hA7f, dcw, dcb, x, oute, outo, 3);

  // step 4 rest: oute = c + x4 ; dadj -> tail
  k_s1h0<<<NNODE, 64, 0, stream>>>(STb, adjW, ggw, ggb, H0);
  k_fc<<<NNODE, 256, 0, stream>>>(H0, fc0w, fc0b, fc1w, fc1b, fc2w, fc2b,
                                  gW + 3*GN, adjW, a_in, dadjW, tail);
  k_hA<<<agrid, 256, 0, stream>>>(H2, h7fB, dadjW, HA, hA7f);
  k_mix<<<mgrid, 256, 0, stream>>>(H2, HA, h7fB, hA7f, dcw, dcb, x, oute, outo, 4);

  (void)in_sizes; (void)n_in; (void)out_size;
}